// Round 7
// baseline (271.828 us; speedup 1.0000x reference)
//
#include <hip/hip_runtime.h>
#include <math.h>

#define WNUM 1792
#define HID 128

#define INV3C 0.5773502691896258f
#define INV2C 0.7071067811865476f
#define A0C   0.17677669529663687f   /* 1/sqrt(32) */
#define A1C   0.14433756729740643f   /* 1/sqrt(48) */

typedef short bf8 __attribute__((ext_vector_type(8)));
typedef _Float16 f16x8 __attribute__((ext_vector_type(8)));
typedef _Float16 f16x4 __attribute__((ext_vector_type(4)));
typedef float f32x4 __attribute__((ext_vector_type(4)));

__device__ inline unsigned short f2bf(float f) {
  union { float f; unsigned u; } v; v.f = f;
  unsigned r = v.u + 0x7FFFu + ((v.u >> 16) & 1u);   // RNE
  return (unsigned short)(r >> 16);
}
__device__ inline float bf2f(unsigned short h) {
  union { unsigned u; float f; } v; v.u = ((unsigned)h) << 16;
  return v.f;
}
__device__ inline float wscale(int t) {   // section constants folded into weights+biases
  if (t < 32) return A0C;
  if (t < 64) return A0C * INV3C;
  if (t < 96) return A1C;
  return A1C * INV2C;
}

// ---- prep: coalesced-write weight staging ----
// we2h: [t(112)][c(4)][lane(64)][j(8)] fp16 = We2[k=c*32+(lane>>4)*8+j][t*16+(lane&15)] * wscale(t)
// we1x: [c1(8)][half][lane(64)][j(8)] bf16 hi/lo of We1[k=(lane>>4)*8+j][c1*16+(lane&15)]
// be2p: [pair(56)][l16(16)][hf(2)] fp32 = be2[(2*pair+hf)*16+l16] * wscale
__global__ __launch_bounds__(256) void prep_kernel(
    const float* __restrict__ We1, const float* __restrict__ We2,
    const float* __restrict__ be2,
    unsigned short* __restrict__ we1x, _Float16* __restrict__ we2h,
    float* __restrict__ be2p)
{
  int i = blockIdx.x * 256 + threadIdx.x;
  if (i < 28672) {                       // we2h: one thread per (t, c, lane) = 112*4*64
    int t = i >> 8, c = (i >> 6) & 3, lane = i & 63;
    int quad = lane >> 4, l15 = lane & 15;
    int col = t * 16 + l15;
    float sc = wscale(t);
    f16x8 v;
    #pragma unroll
    for (int j = 0; j < 8; ++j) {
      int k = c * 32 + quad * 8 + j;
      v[j] = (_Float16)(We2[(size_t)k * WNUM + col] * sc);
    }
    *(f16x8*)(we2h + (size_t)t * 2048 + c * 512 + lane * 8) = v;
  } else if (i < 29184) {                // we1x: one thread per (c1, lane) = 8*64 = 512
    int q = i - 28672;
    int c1 = q >> 6, lane = q & 63;
    int quad = lane >> 4, l15 = lane & 15;
    int col = c1 * 16 + l15;
    bf8 hh, ll;
    #pragma unroll
    for (int j = 0; j < 8; ++j) {
      int k = quad * 8 + j;
      float v = We1[k * HID + col];
      unsigned short hi = f2bf(v);
      hh[j] = (short)hi;
      ll[j] = (short)f2bf(v - bf2f(hi));
    }
    *(bf8*)(we1x + c1 * 1024 + lane * 8) = hh;
    *(bf8*)(we1x + c1 * 1024 + 512 + lane * 8) = ll;
  } else if (i < 30976) {                // be2p: 1792 entries
    int q = i - 29184;                   // q = t*16 + l16
    int t = q >> 4, l16 = q & 15;
    be2p[(t >> 1) * 32 + l16 * 2 + (t & 1)] = be2[q] * wscale(t);
  }
}

struct Pair { f16x8 b0, b1, b2, b3, b4, b5, b6, b7; float2 bias; };

__device__ inline void load_pair(Pair& P, const _Float16* bW, const float* bp, int p) {
  const _Float16* q = bW + (size_t)p * 4096;
  P.b0 = *(const f16x8*)(q);
  P.b1 = *(const f16x8*)(q + 512);
  P.b2 = *(const f16x8*)(q + 1024);
  P.b3 = *(const f16x8*)(q + 1536);
  P.b4 = *(const f16x8*)(q + 2048);
  P.b5 = *(const f16x8*)(q + 2560);
  P.b6 = *(const f16x8*)(q + 3072);
  P.b7 = *(const f16x8*)(q + 3584);
  P.bias = *(const float2*)(bp + p * 32);
}

__device__ inline void chains(const f16x8* af, const Pair& P, f32x4& wa, f32x4& wb) {
  f32x4 ca = {P.bias.x, P.bias.x, P.bias.x, P.bias.x};
  f32x4 cb = {P.bias.y, P.bias.y, P.bias.y, P.bias.y};
  ca = __builtin_amdgcn_mfma_f32_16x16x32_f16(af[0], P.b0, ca, 0, 0, 0);
  cb = __builtin_amdgcn_mfma_f32_16x16x32_f16(af[0], P.b4, cb, 0, 0, 0);
  ca = __builtin_amdgcn_mfma_f32_16x16x32_f16(af[1], P.b1, ca, 0, 0, 0);
  cb = __builtin_amdgcn_mfma_f32_16x16x32_f16(af[1], P.b5, cb, 0, 0, 0);
  ca = __builtin_amdgcn_mfma_f32_16x16x32_f16(af[2], P.b2, ca, 0, 0, 0);
  cb = __builtin_amdgcn_mfma_f32_16x16x32_f16(af[2], P.b6, cb, 0, 0, 0);
  ca = __builtin_amdgcn_mfma_f32_16x16x32_f16(af[3], P.b3, ca, 0, 0, 0);
  cb = __builtin_amdgcn_mfma_f32_16x16x32_f16(af[3], P.b7, cb, 0, 0, 0);
  wa = ca; wb = cb;
}

// ---- fused edge kernel ----
__global__ __launch_bounds__(256, 4) void edge_kernel(
    const float* __restrict__ ea, const float* __restrict__ xsrc,
    const float* __restrict__ sh, const int* __restrict__ dst,
    const float* __restrict__ be1,
    const unsigned short* __restrict__ we1x, const _Float16* __restrict__ we2h,
    const float* __restrict__ be2p,
    float* __restrict__ accn, float* __restrict__ cnt, int E)
{
  const int lane = threadIdx.x & 63;
  const int w    = threadIdx.x >> 6;
  const int quad = lane >> 4;
  const int l16  = lane & 15;
  const int eb   = (blockIdx.x * 4 + w) * 16;

  __shared__ _Float16 h_s[4][16][136];         // fp16 h  (17.4 KB)
  __shared__ _Float16 fss_s[4][16][16];        // s1*s2   (2 KB)
  __shared__ _Float16 fvv_s[4][16][16];        // v1.v2   (2 KB)
  __shared__ float s1_s[4][16][16];            // s1      (4 KB)
  __shared__ float v1_s[4][16][3][16];         // v1[m][c][e] (12 KB)
  __shared__ float4 vq_s[4][16];               // {v2x,v2y,v2z,s2} (1 KB)

  // ---- stage per-edge factors (lane -> e = lane>>2, m-group = lane&3) ----
  {
    int e2 = lane >> 2, mg = lane & 3;
    int ge = eb + e2;
    if (ge < E) {
      const float* xp = xsrc + (size_t)ge * 64;
      float4 s1q = *(const float4*)(xp + mg * 4);
      const float* vp = xp + 16 + mg * 12;
      float4 va = *(const float4*)(vp);
      float4 vb = *(const float4*)(vp + 4);
      float4 vc = *(const float4*)(vp + 8);
      float la[12] = {va.x,va.y,va.z,va.w,vb.x,vb.y,vb.z,vb.w,vc.x,vc.y,vc.z,vc.w};
      float s1a[4] = {s1q.x, s1q.y, s1q.z, s1q.w};
      float4 shq = *(const float4*)(sh + (size_t)ge * 4);
      float s2 = shq.x, v2x = shq.y, v2y = shq.z, v2z = shq.w;
      #pragma unroll
      for (int mi = 0; mi < 4; ++mi) {
        int m = mg * 4 + mi;
        float v1x = la[mi*3], v1y = la[mi*3+1], v1z = la[mi*3+2];
        s1_s[w][m][e2] = s1a[mi];
        fss_s[w][m][e2] = (_Float16)(s1a[mi] * s2);
        fvv_s[w][m][e2] = (_Float16)(v1x*v2x + v1y*v2y + v1z*v2z);
        v1_s[w][m][0][e2] = v1x;
        v1_s[w][m][1][e2] = v1y;
        v1_s[w][m][2][e2] = v1z;
      }
      if (mg == 0) vq_s[w][e2] = make_float4(v2x, v2y, v2z, s2);
    } else {
      #pragma unroll
      for (int mi = 0; mi < 4; ++mi) {
        int m = mg * 4 + mi;
        s1_s[w][m][e2] = 0.f;
        fss_s[w][m][e2] = (_Float16)0.f;
        fvv_s[w][m][e2] = (_Float16)0.f;
        v1_s[w][m][0][e2] = 0.f; v1_s[w][m][1][e2] = 0.f; v1_s[w][m][2][e2] = 0.f;
      }
      if (mg == 0) vq_s[w][e2] = make_float4(0,0,0,0);
    }
  }

  // ---- layer 1: h = relu(ea @ We1 + be1), split-bf16 MFMA, fp16 h to LDS ----
  {
    int gea = eb + l16; if (gea > E - 1) gea = E - 1;
    const float* ep = ea + (size_t)gea * 32 + quad * 8;
    float4 p0 = *(const float4*)ep;
    float4 p1 = *(const float4*)(ep + 4);
    float pv[8] = {p0.x,p0.y,p0.z,p0.w,p1.x,p1.y,p1.z,p1.w};
    bf8 ah, al;
    #pragma unroll
    for (int j = 0; j < 8; ++j) {
      unsigned short hi = f2bf(pv[j]);
      ah[j] = (short)hi;
      al[j] = (short)f2bf(pv[j] - bf2f(hi));
    }
    const unsigned short* wb1 = we1x + lane * 8;
    #pragma unroll 2
    for (int c = 0; c < 8; ++c) {
      bf8 bh = *(const bf8*)(wb1 + c * 1024);
      bf8 bl = *(const bf8*)(wb1 + c * 1024 + 512);
      float bias = be1[c * 16 + l16];
      f32x4 hc = {bias, bias, bias, bias};
      hc = __builtin_amdgcn_mfma_f32_16x16x32_bf16(al, bh, hc, 0, 0, 0);
      hc = __builtin_amdgcn_mfma_f32_16x16x32_bf16(ah, bl, hc, 0, 0, 0);
      hc = __builtin_amdgcn_mfma_f32_16x16x32_bf16(ah, bh, hc, 0, 0, 0);
      #pragma unroll
      for (int r = 0; r < 4; ++r)
        h_s[w][quad * 4 + r][c * 16 + l16] = (_Float16)fmaxf(hc[r], 0.f);
    }
  }
  __syncthreads();

  // ---- A fragments (fp16 h) for the whole column loop ----
  f16x8 af[4];
  #pragma unroll
  for (int ch = 0; ch < 4; ++ch)
    af[ch] = *(const f16x8*)&h_s[w][l16][ch * 32 + quad * 8];

  float4 vq[4];
  #pragma unroll
  for (int r = 0; r < 4; ++r) vq[r] = vq_s[w][quad * 4 + r];

  float m0a[4] = {0,0,0,0}, m0b[4] = {0,0,0,0};
  float m1x[4] = {0,0,0,0}, m1y[4] = {0,0,0,0}, m1z[4] = {0,0,0,0};

  const _Float16* bW = we2h + lane * 8;
  const float* bp = be2p + l16 * 2;

  Pair cur, nxt;

  // ---- section 1: ss (pairs 0..15), out0 += w * (s1*s2) ----
  load_pair(cur, bW, bp, 0);
  #pragma unroll 1
  for (int i = 0; i < 16; i += 2) {
    load_pair(nxt, bW, bp, i + 1);
    {
      f32x4 wa, wb; chains(af, cur, wa, wb);
      f16x4 fv = *(const f16x4*)&fss_s[w][i][quad * 4];
      #pragma unroll
      for (int r = 0; r < 4; ++r) {
        float f = (float)fv[r];
        m0a[r] = fmaf(wa[r], f, m0a[r]);
        m0b[r] = fmaf(wb[r], f, m0b[r]);
      }
    }
    load_pair(cur, bW, bp, i + 2);
    {
      f32x4 wa, wb; chains(af, nxt, wa, wb);
      f16x4 fv = *(const f16x4*)&fss_s[w][i + 1][quad * 4];
      #pragma unroll
      for (int r = 0; r < 4; ++r) {
        float f = (float)fv[r];
        m0a[r] = fmaf(wa[r], f, m0a[r]);
        m0b[r] = fmaf(wb[r], f, m0b[r]);
      }
    }
  }

  // ---- section 2: vv0 (pairs 16..31), out0 += w * (v1.v2)   [INV3 folded] ----
  #pragma unroll 1
  for (int i = 0; i < 16; i += 2) {
    load_pair(nxt, bW, bp, 17 + i);
    {
      f32x4 wa, wb; chains(af, cur, wa, wb);
      f16x4 fv = *(const f16x4*)&fvv_s[w][i][quad * 4];
      #pragma unroll
      for (int r = 0; r < 4; ++r) {
        float f = (float)fv[r];
        m0a[r] = fmaf(wa[r], f, m0a[r]);
        m0b[r] = fmaf(wb[r], f, m0b[r]);
      }
    }
    load_pair(cur, bW, bp, 18 + i);
    {
      f32x4 wa, wb; chains(af, nxt, wa, wb);
      f16x4 fv = *(const f16x4*)&fvv_s[w][i + 1][quad * 4];
      #pragma unroll
      for (int r = 0; r < 4; ++r) {
        float f = (float)fv[r];
        m0a[r] = fmaf(wa[r], f, m0a[r]);
        m0b[r] = fmaf(wb[r], f, m0b[r]);
      }
    }
  }

  // ---- section 3: sv (pairs 32..39), sigma = sum w*s1; then m1 += sigma*v2 ----
  {
    float sg[4] = {0,0,0,0};
    #pragma unroll 1
    for (int i = 0; i < 8; i += 2) {
      load_pair(nxt, bW, bp, 33 + i);
      {
        f32x4 wa, wb; chains(af, cur, wa, wb);
        f32x4 sA = *(const f32x4*)&s1_s[w][2*i][quad * 4];
        f32x4 sB = *(const f32x4*)&s1_s[w][2*i + 1][quad * 4];
        #pragma unroll
        for (int r = 0; r < 4; ++r)
          sg[r] = fmaf(wb[r], sB[r], fmaf(wa[r], sA[r], sg[r]));
      }
      load_pair(cur, bW, bp, 34 + i);
      {
        f32x4 wa, wb; chains(af, nxt, wa, wb);
        f32x4 sA = *(const f32x4*)&s1_s[w][2*i + 2][quad * 4];
        f32x4 sB = *(const f32x4*)&s1_s[w][2*i + 3][quad * 4];
        #pragma unroll
        for (int r = 0; r < 4; ++r)
          sg[r] = fmaf(wb[r], sB[r], fmaf(wa[r], sA[r], sg[r]));
      }
    }
    #pragma unroll
    for (int r = 0; r < 4; ++r) {
      m1x[r] = fmaf(sg[r], vq[r].x, m1x[r]);
      m1y[r] = fmaf(sg[r], vq[r].y, m1y[r]);
      m1z[r] = fmaf(sg[r], vq[r].z, m1z[r]);
    }
  }

  // ---- section 4: vs (pairs 40..47), u = sum w*v1; then m1 += s2*u ----
  {
    float ux[4] = {0,0,0,0}, uy[4] = {0,0,0,0}, uz[4] = {0,0,0,0};
    #pragma unroll 1
    for (int i = 0; i < 8; i += 2) {
      load_pair(nxt, bW, bp, 41 + i);
      {
        f32x4 wa, wb; chains(af, cur, wa, wb);
        f32x4 xA = *(const f32x4*)&v1_s[w][2*i][0][quad*4], xB = *(const f32x4*)&v1_s[w][2*i+1][0][quad*4];
        f32x4 yA = *(const f32x4*)&v1_s[w][2*i][1][quad*4], yB = *(const f32x4*)&v1_s[w][2*i+1][1][quad*4];
        f32x4 zA = *(const f32x4*)&v1_s[w][2*i][2][quad*4], zB = *(const f32x4*)&v1_s[w][2*i+1][2][quad*4];
        #pragma unroll
        for (int r = 0; r < 4; ++r) {
          ux[r] = fmaf(wb[r], xB[r], fmaf(wa[r], xA[r], ux[r]));
          uy[r] = fmaf(wb[r], yB[r], fmaf(wa[r], yA[r], uy[r]));
          uz[r] = fmaf(wb[r], zB[r], fmaf(wa[r], zA[r], uz[r]));
        }
      }
      load_pair(cur, bW, bp, 42 + i);
      {
        f32x4 wa, wb; chains(af, nxt, wa, wb);
        f32x4 xA = *(const f32x4*)&v1_s[w][2*i+2][0][quad*4], xB = *(const f32x4*)&v1_s[w][2*i+3][0][quad*4];
        f32x4 yA = *(const f32x4*)&v1_s[w][2*i+2][1][quad*4], yB = *(const f32x4*)&v1_s[w][2*i+3][1][quad*4];
        f32x4 zA = *(const f32x4*)&v1_s[w][2*i+2][2][quad*4], zB = *(const f32x4*)&v1_s[w][2*i+3][2][quad*4];
        #pragma unroll
        for (int r = 0; r < 4; ++r) {
          ux[r] = fmaf(wb[r], xB[r], fmaf(wa[r], xA[r], ux[r]));
          uy[r] = fmaf(wb[r], yB[r], fmaf(wa[r], yA[r], uy[r]));
          uz[r] = fmaf(wb[r], zB[r], fmaf(wa[r], zA[r], uz[r]));
        }
      }
    }
    #pragma unroll
    for (int r = 0; r < 4; ++r) {
      m1x[r] = fmaf(vq[r].w, ux[r], m1x[r]);
      m1y[r] = fmaf(vq[r].w, uy[r], m1y[r]);
      m1z[r] = fmaf(vq[r].w, uz[r], m1z[r]);
    }
  }

  // ---- section 5: vv1 (pairs 48..55), u = sum w*v1; then m1 += cross(u, v2)  [INV2 folded] ----
  {
    float ux[4] = {0,0,0,0}, uy[4] = {0,0,0,0}, uz[4] = {0,0,0,0};
    #pragma unroll 1
    for (int i = 0; i < 8; i += 2) {
      load_pair(nxt, bW, bp, 49 + i);
      {
        f32x4 wa, wb; chains(af, cur, wa, wb);
        f32x4 xA = *(const f32x4*)&v1_s[w][2*i][0][quad*4], xB = *(const f32x4*)&v1_s[w][2*i+1][0][quad*4];
        f32x4 yA = *(const f32x4*)&v1_s[w][2*i][1][quad*4], yB = *(const f32x4*)&v1_s[w][2*i+1][1][quad*4];
        f32x4 zA = *(const f32x4*)&v1_s[w][2*i][2][quad*4], zB = *(const f32x4*)&v1_s[w][2*i+1][2][quad*4];
        #pragma unroll
        for (int r = 0; r < 4; ++r) {
          ux[r] = fmaf(wb[r], xB[r], fmaf(wa[r], xA[r], ux[r]));
          uy[r] = fmaf(wb[r], yB[r], fmaf(wa[r], yA[r], uy[r]));
          uz[r] = fmaf(wb[r], zB[r], fmaf(wa[r], zA[r], uz[r]));
        }
      }
      load_pair(cur, bW, bp, 50 + i);
      {
        f32x4 wa, wb; chains(af, nxt, wa, wb);
        f32x4 xA = *(const f32x4*)&v1_s[w][2*i+2][0][quad*4], xB = *(const f32x4*)&v1_s[w][2*i+3][0][quad*4];
        f32x4 yA = *(const f32x4*)&v1_s[w][2*i+2][1][quad*4], yB = *(const f32x4*)&v1_s[w][2*i+3][1][quad*4];
        f32x4 zA = *(const f32x4*)&v1_s[w][2*i+2][2][quad*4], zB = *(const f32x4*)&v1_s[w][2*i+3][2][quad*4];
        #pragma unroll
        for (int r = 0; r < 4; ++r) {
          ux[r] = fmaf(wb[r], xB[r], fmaf(wa[r], xA[r], ux[r]));
          uy[r] = fmaf(wb[r], yB[r], fmaf(wa[r], yA[r], uy[r]));
          uz[r] = fmaf(wb[r], zB[r], fmaf(wa[r], zA[r], uz[r]));
        }
      }
    }
    #pragma unroll
    for (int r = 0; r < 4; ++r) {
      m1x[r] = fmaf(uy[r], vq[r].z, m1x[r]); m1x[r] = fmaf(-uz[r], vq[r].y, m1x[r]);
      m1y[r] = fmaf(uz[r], vq[r].x, m1y[r]); m1y[r] = fmaf(-ux[r], vq[r].z, m1y[r]);
      m1z[r] = fmaf(ux[r], vq[r].y, m1z[r]); m1z[r] = fmaf(-uy[r], vq[r].x, m1z[r]);
    }
  }

  // ---- scatter to node accumulators (constants already folded into weights) ----
  #pragma unroll
  for (int r = 0; r < 4; ++r) {
    int ge = eb + quad * 4 + r;
    if (ge < E) {
      int node = dst[ge];
      float* ap = accn + (size_t)node * 80;
      atomicAdd(ap + l16,            m0a[r]);
      atomicAdd(ap + 16 + l16,       m0b[r]);
      atomicAdd(ap + 32 + l16*3 + 0, m1x[r]);
      atomicAdd(ap + 32 + l16*3 + 1, m1y[r]);
      atomicAdd(ap + 32 + l16*3 + 2, m1z[r]);
    }
  }
  if (lane < 16) {
    int ge = eb + lane;
    if (ge < E) atomicAdd(cnt + dst[ge], 1.0f);
  }
}

// ---- node epilogue: 64 threads per node ----
__global__ __launch_bounds__(256) void node_kernel(
    const float* __restrict__ accn, const float* __restrict__ cnt,
    const float* __restrict__ xdst, const float* __restrict__ Wr0,
    const float* __restrict__ Wr1, float* __restrict__ out, int N)
{
  int idx = blockIdx.x * 256 + threadIdx.x;
  int n = idx >> 6, j = idx & 63;
  if (n >= N) return;
  float inv = 1.0f / fmaxf(cnt[n], 1.0f);
  const float* ap = accn + (size_t)n * 80;
  const float* xd = xdst + (size_t)n * 64;
  float* op = out + (size_t)n * 64;
  if (j < 16) {
    float s = 0.f;
    #pragma unroll
    for (int m = 0; m < 16; ++m) s = fmaf(xd[m], Wr0[m * 32 + j], s);
    op[j] = fmaxf(ap[j] * inv + 0.25f * s, 0.f);
  } else {
    int jj = j - 16;
    int o = (jj * 86) >> 8;          // jj / 3 for jj < 48
    int c = jj - o * 3;
    float tg = 0.f, v = 0.f;
    #pragma unroll
    for (int m = 0; m < 16; ++m) {
      tg = fmaf(xd[m], Wr0[m * 32 + 16 + o], tg);
      v  = fmaf(xd[16 + m * 3 + c], Wr1[m * 16 + o], v);
    }
    float g = 1.0f / (1.0f + expf(-(ap[16 + o] * inv + 0.25f * tg)));
    op[16 + jj] = (ap[32 + jj] * inv + 0.25f * v) * g;
  }
}

extern "C" void kernel_launch(void* const* d_in, const int* in_sizes, int n_in,
                              void* d_out, int out_size, void* d_ws, size_t ws_size,
                              hipStream_t stream)
{
  const int*   dst  = (const int*)d_in[0];
  const float* xsrc = (const float*)d_in[1];
  const float* xdst = (const float*)d_in[2];
  const float* sh   = (const float*)d_in[3];
  const float* ea   = (const float*)d_in[4];
  const float* We1  = (const float*)d_in[5];
  const float* be1  = (const float*)d_in[6];
  const float* We2  = (const float*)d_in[7];
  const float* be2  = (const float*)d_in[8];
  const float* Wr0  = (const float*)d_in[9];
  const float* Wr1  = (const float*)d_in[10];
  const int E = in_sizes[0];
  const int N = in_sizes[2] / 64;

  char* ws = (char*)d_ws;
  _Float16* we2h = (_Float16*)ws;                           // 458,752 B
  unsigned short* we1x = (unsigned short*)(ws + 458752);    //  16,384 B
  float* be2p = (float*)(ws + 475136);                      //   7,424 B
  float* accn = (float*)(ws + 482560);                      // N*80*4
  float* cnt  = (float*)(ws + 482560 + (size_t)N * 320);    // N*4

  hipMemsetAsync(accn, 0, (size_t)N * 320 + (size_t)N * 4, stream);

  prep_kernel<<<(30976 + 255) / 256, 256, 0, stream>>>(We1, We2, be2, we1x, we2h, be2p);
  edge_kernel<<<(E + 63) / 64, 256, 0, stream>>>(ea, xsrc, sh, dst, be1,
      we1x, we2h, be2p, accn, cnt, E);
  node_kernel<<<((size_t)N * 64 + 255) / 256, 256, 0, stream>>>(accn, cnt, xdst, Wr0, Wr1,
      (float*)d_out, N);
}

// Round 8
// 239.108 us; speedup vs baseline: 1.1368x; 1.1368x over previous
//
#include <hip/hip_runtime.h>
#include <math.h>

#define WNUM 1792
#define HID 128

#define INV3C 0.5773502691896258f
#define INV2C 0.7071067811865476f
#define A0C   0.17677669529663687f   /* 1/sqrt(32) */
#define A1C   0.14433756729740643f   /* 1/sqrt(48) */

typedef short bf8 __attribute__((ext_vector_type(8)));
typedef _Float16 f16x8 __attribute__((ext_vector_type(8)));
typedef _Float16 f16x4 __attribute__((ext_vector_type(4)));
typedef float f32x4 __attribute__((ext_vector_type(4)));

__device__ inline unsigned short f2bf(float f) {
  union { float f; unsigned u; } v; v.f = f;
  unsigned r = v.u + 0x7FFFu + ((v.u >> 16) & 1u);   // RNE
  return (unsigned short)(r >> 16);
}
__device__ inline float bf2f(unsigned short h) {
  union { unsigned u; float f; } v; v.u = ((unsigned)h) << 16;
  return v.f;
}
__device__ inline float wscale(int t) {   // section constants folded into weights+biases
  if (t < 32) return A0C;
  if (t < 64) return A0C * INV3C;
  if (t < 96) return A1C;
  return A1C * INV2C;
}

// ---- prep: coalesced-write weight staging (unchanged layouts from R7) ----
__global__ __launch_bounds__(256) void prep_kernel(
    const float* __restrict__ We1, const float* __restrict__ We2,
    const float* __restrict__ be2,
    unsigned short* __restrict__ we1x, _Float16* __restrict__ we2h,
    float* __restrict__ be2p)
{
  int i = blockIdx.x * 256 + threadIdx.x;
  if (i < 28672) {                       // we2h: one thread per (t, c, lane) = 112*4*64
    int t = i >> 8, c = (i >> 6) & 3, lane = i & 63;
    int quad = lane >> 4, l15 = lane & 15;
    int col = t * 16 + l15;
    float sc = wscale(t);
    f16x8 v;
    #pragma unroll
    for (int j = 0; j < 8; ++j) {
      int k = c * 32 + quad * 8 + j;
      v[j] = (_Float16)(We2[(size_t)k * WNUM + col] * sc);
    }
    *(f16x8*)(we2h + (size_t)t * 2048 + c * 512 + lane * 8) = v;
  } else if (i < 29184) {                // we1x: one thread per (c1, lane) = 512
    int q = i - 28672;
    int c1 = q >> 6, lane = q & 63;
    int quad = lane >> 4, l15 = lane & 15;
    int col = c1 * 16 + l15;
    bf8 hh, ll;
    #pragma unroll
    for (int j = 0; j < 8; ++j) {
      int k = quad * 8 + j;
      float v = We1[k * HID + col];
      unsigned short hi = f2bf(v);
      hh[j] = (short)hi;
      ll[j] = (short)f2bf(v - bf2f(hi));
    }
    *(bf8*)(we1x + c1 * 1024 + lane * 8) = hh;
    *(bf8*)(we1x + c1 * 1024 + 512 + lane * 8) = ll;
  } else if (i < 30976) {                // be2p: 1792 entries
    int q = i - 29184;                   // q = t*16 + l16
    int t = q >> 4, l16 = q & 15;
    be2p[(t >> 1) * 32 + l16 * 2 + (t & 1)] = be2[q] * wscale(t);
  }
}

// 16 MFMAs: two edge-groups x two tiles, 4 independent chains of 4
__device__ inline void chains2(const f16x8* a0, const f16x8* a1,
    f16x8 b0, f16x8 b1, f16x8 b2, f16x8 b3,
    f16x8 b4, f16x8 b5, f16x8 b6, f16x8 b7,
    float2 bias, f32x4* wa, f32x4* wb)
{
  f32x4 ca0 = {bias.x, bias.x, bias.x, bias.x};
  f32x4 cb0 = {bias.y, bias.y, bias.y, bias.y};
  f32x4 ca1 = ca0, cb1 = cb0;
  ca0 = __builtin_amdgcn_mfma_f32_16x16x32_f16(a0[0], b0, ca0, 0, 0, 0);
  cb0 = __builtin_amdgcn_mfma_f32_16x16x32_f16(a0[0], b4, cb0, 0, 0, 0);
  ca1 = __builtin_amdgcn_mfma_f32_16x16x32_f16(a1[0], b0, ca1, 0, 0, 0);
  cb1 = __builtin_amdgcn_mfma_f32_16x16x32_f16(a1[0], b4, cb1, 0, 0, 0);
  ca0 = __builtin_amdgcn_mfma_f32_16x16x32_f16(a0[1], b1, ca0, 0, 0, 0);
  cb0 = __builtin_amdgcn_mfma_f32_16x16x32_f16(a0[1], b5, cb0, 0, 0, 0);
  ca1 = __builtin_amdgcn_mfma_f32_16x16x32_f16(a1[1], b1, ca1, 0, 0, 0);
  cb1 = __builtin_amdgcn_mfma_f32_16x16x32_f16(a1[1], b5, cb1, 0, 0, 0);
  ca0 = __builtin_amdgcn_mfma_f32_16x16x32_f16(a0[2], b2, ca0, 0, 0, 0);
  cb0 = __builtin_amdgcn_mfma_f32_16x16x32_f16(a0[2], b6, cb0, 0, 0, 0);
  ca1 = __builtin_amdgcn_mfma_f32_16x16x32_f16(a1[2], b2, ca1, 0, 0, 0);
  cb1 = __builtin_amdgcn_mfma_f32_16x16x32_f16(a1[2], b6, cb1, 0, 0, 0);
  ca0 = __builtin_amdgcn_mfma_f32_16x16x32_f16(a0[3], b3, ca0, 0, 0, 0);
  cb0 = __builtin_amdgcn_mfma_f32_16x16x32_f16(a0[3], b7, cb0, 0, 0, 0);
  ca1 = __builtin_amdgcn_mfma_f32_16x16x32_f16(a1[3], b3, ca1, 0, 0, 0);
  cb1 = __builtin_amdgcn_mfma_f32_16x16x32_f16(a1[3], b7, cb1, 0, 0, 0);
  wa[0] = ca0; wb[0] = cb0; wa[1] = ca1; wb[1] = cb1;
}

#define LOADB(P) \
  f16x8 b0, b1, b2, b3, b4, b5, b6, b7; float2 bias2; \
  { const _Float16* q_ = bW + (size_t)(P) * 4096; \
    b0 = *(const f16x8*)(q_);        b1 = *(const f16x8*)(q_ + 512); \
    b2 = *(const f16x8*)(q_ + 1024); b3 = *(const f16x8*)(q_ + 1536); \
    b4 = *(const f16x8*)(q_ + 2048); b5 = *(const f16x8*)(q_ + 2560); \
    b6 = *(const f16x8*)(q_ + 3072); b7 = *(const f16x8*)(q_ + 3584); \
    bias2 = *(const float2*)(bp + (P) * 32); }

// ---- fused edge kernel: 128 threads = 2 waves, 32 edges per wave ----
__global__ __launch_bounds__(128, 2) void edge_kernel(
    const float* __restrict__ ea, const float* __restrict__ xsrc,
    const float* __restrict__ sh, const int* __restrict__ dst,
    const float* __restrict__ be1,
    const unsigned short* __restrict__ we1x, const _Float16* __restrict__ we2h,
    const float* __restrict__ be2p,
    float* __restrict__ accn, float* __restrict__ cnt, int E)
{
  const int lane = threadIdx.x & 63;
  const int w    = threadIdx.x >> 6;       // 0..1
  const int quad = lane >> 4;
  const int l16  = lane & 15;
  const int eb   = (blockIdx.x * 2 + w) * 32;

  __shared__ _Float16 h_s[2][32][136];        // 17.4 KB
  __shared__ _Float16 fss_s[2][16][32];       // 2 KB  s1*s2
  __shared__ _Float16 fvv_s[2][16][32];       // 2 KB  v1.v2
  __shared__ _Float16 s1h_s[2][16][32];       // 2 KB
  __shared__ _Float16 v1h_s[2][16][3][32];    // 6 KB
  __shared__ float4 vq_s[2][32];              // 1 KB  {v2x,v2y,v2z,s2}

  // ---- stage per-edge factors (lane -> e2 = lane>>1, m-half = lane&1) ----
  {
    int e2 = lane >> 1, mg = lane & 1;
    int ge = eb + e2;
    if (ge < E) {
      const float* xp = xsrc + (size_t)ge * 64;
      float4 sq0 = *(const float4*)(xp + mg * 8);
      float4 sq1 = *(const float4*)(xp + mg * 8 + 4);
      float s1a[8] = {sq0.x,sq0.y,sq0.z,sq0.w,sq1.x,sq1.y,sq1.z,sq1.w};
      const float* vp = xp + 16 + mg * 24;
      float la[24];
      #pragma unroll
      for (int qv = 0; qv < 6; ++qv) {
        float4 t = *(const float4*)(vp + qv * 4);
        la[qv*4+0] = t.x; la[qv*4+1] = t.y; la[qv*4+2] = t.z; la[qv*4+3] = t.w;
      }
      float4 shq = *(const float4*)(sh + (size_t)ge * 4);
      float s2 = shq.x, v2x = shq.y, v2y = shq.z, v2z = shq.w;
      #pragma unroll
      for (int mi = 0; mi < 8; ++mi) {
        int m = mg * 8 + mi;
        float v1x = la[mi*3], v1y = la[mi*3+1], v1z = la[mi*3+2];
        fss_s[w][m][e2] = (_Float16)(s1a[mi] * s2);
        fvv_s[w][m][e2] = (_Float16)(v1x*v2x + v1y*v2y + v1z*v2z);
        s1h_s[w][m][e2] = (_Float16)s1a[mi];
        v1h_s[w][m][0][e2] = (_Float16)v1x;
        v1h_s[w][m][1][e2] = (_Float16)v1y;
        v1h_s[w][m][2][e2] = (_Float16)v1z;
      }
      if (mg == 0) vq_s[w][e2] = make_float4(v2x, v2y, v2z, s2);
    } else {
      #pragma unroll
      for (int mi = 0; mi < 8; ++mi) {
        int m = mg * 8 + mi;
        fss_s[w][m][e2] = (_Float16)0.f;
        fvv_s[w][m][e2] = (_Float16)0.f;
        s1h_s[w][m][e2] = (_Float16)0.f;
        v1h_s[w][m][0][e2] = (_Float16)0.f;
        v1h_s[w][m][1][e2] = (_Float16)0.f;
        v1h_s[w][m][2][e2] = (_Float16)0.f;
      }
      if (mg == 0) vq_s[w][e2] = make_float4(0,0,0,0);
    }
  }

  // ---- layer 1: two 16-edge groups, B-fragments shared across groups ----
  {
    bf8 ah[2], al[2];
    #pragma unroll
    for (int g = 0; g < 2; ++g) {
      int gea = eb + g * 16 + l16; if (gea > E - 1) gea = E - 1;
      const float* ep = ea + (size_t)gea * 32 + quad * 8;
      float4 p0 = *(const float4*)ep;
      float4 p1 = *(const float4*)(ep + 4);
      float pv[8] = {p0.x,p0.y,p0.z,p0.w,p1.x,p1.y,p1.z,p1.w};
      #pragma unroll
      for (int j = 0; j < 8; ++j) {
        unsigned short hi = f2bf(pv[j]);
        ah[g][j] = (short)hi;
        al[g][j] = (short)f2bf(pv[j] - bf2f(hi));
      }
    }
    const unsigned short* wb1 = we1x + lane * 8;
    #pragma unroll 2
    for (int c = 0; c < 8; ++c) {
      bf8 bh = *(const bf8*)(wb1 + c * 1024);
      bf8 bl = *(const bf8*)(wb1 + c * 1024 + 512);
      float bias = be1[c * 16 + l16];
      #pragma unroll
      for (int g = 0; g < 2; ++g) {
        f32x4 hc = {bias, bias, bias, bias};
        hc = __builtin_amdgcn_mfma_f32_16x16x32_bf16(al[g], bh, hc, 0, 0, 0);
        hc = __builtin_amdgcn_mfma_f32_16x16x32_bf16(ah[g], bl, hc, 0, 0, 0);
        hc = __builtin_amdgcn_mfma_f32_16x16x32_bf16(ah[g], bh, hc, 0, 0, 0);
        #pragma unroll
        for (int r = 0; r < 4; ++r)
          h_s[w][g * 16 + quad * 4 + r][c * 16 + l16] = (_Float16)fmaxf(hc[r], 0.f);
      }
    }
  }
  __syncthreads();

  // ---- A fragments for both groups ----
  f16x8 af[2][4];
  #pragma unroll
  for (int g = 0; g < 2; ++g)
    #pragma unroll
    for (int ch = 0; ch < 4; ++ch)
      af[g][ch] = *(const f16x8*)&h_s[w][g * 16 + l16][ch * 32 + quad * 8];

  const _Float16* bW = we2h + lane * 8;
  const float* bp = be2p + l16 * 2;

  float m0a[2][4] = {{0,0,0,0},{0,0,0,0}}, m0b[2][4] = {{0,0,0,0},{0,0,0,0}};

  // ---- section 1: ss (pairs 0..15), out0 += w * (s1*s2) ----
  #pragma unroll 1
  for (int i = 0; i < 16; ++i) {
    LOADB(i)
    f32x4 wa[2], wb[2];
    chains2(af[0], af[1], b0,b1,b2,b3,b4,b5,b6,b7, bias2, wa, wb);
    #pragma unroll
    for (int g = 0; g < 2; ++g) {
      f16x4 fv = *(const f16x4*)&fss_s[w][i][g * 16 + quad * 4];
      #pragma unroll
      for (int r = 0; r < 4; ++r) {
        float f = (float)fv[r];
        m0a[g][r] = fmaf(wa[g][r], f, m0a[g][r]);
        m0b[g][r] = fmaf(wb[g][r], f, m0b[g][r]);
      }
    }
  }

  // ---- section 2: vv0 (pairs 16..31), out0 += w * (v1.v2) [INV3 folded] ----
  #pragma unroll 1
  for (int i = 0; i < 16; ++i) {
    LOADB(16 + i)
    f32x4 wa[2], wb[2];
    chains2(af[0], af[1], b0,b1,b2,b3,b4,b5,b6,b7, bias2, wa, wb);
    #pragma unroll
    for (int g = 0; g < 2; ++g) {
      f16x4 fv = *(const f16x4*)&fvv_s[w][i][g * 16 + quad * 4];
      #pragma unroll
      for (int r = 0; r < 4; ++r) {
        float f = (float)fv[r];
        m0a[g][r] = fmaf(wa[g][r], f, m0a[g][r]);
        m0b[g][r] = fmaf(wb[g][r], f, m0b[g][r]);
      }
    }
  }

  // ---- scatter out0 now (frees registers) + counts ----
  #pragma unroll
  for (int g = 0; g < 2; ++g)
    #pragma unroll
    for (int r = 0; r < 4; ++r) {
      int ge = eb + g * 16 + quad * 4 + r;
      if (ge < E) {
        float* ap = accn + (size_t)dst[ge] * 80;
        atomicAdd(ap + l16,      m0a[g][r]);
        atomicAdd(ap + 16 + l16, m0b[g][r]);
      }
    }
  if (lane < 32) {
    int ge = eb + lane;
    if (ge < E) atomicAdd(cnt + dst[ge], 1.0f);
  }

  // ---- section 3: sv (pairs 32..39), sigma = sum w*s1; m1 = sigma*v2 ----
  float sg[2][4] = {{0,0,0,0},{0,0,0,0}};
  #pragma unroll 1
  for (int i = 0; i < 8; ++i) {
    LOADB(32 + i)
    f32x4 wa[2], wb[2];
    chains2(af[0], af[1], b0,b1,b2,b3,b4,b5,b6,b7, bias2, wa, wb);
    #pragma unroll
    for (int g = 0; g < 2; ++g) {
      f16x4 sA = *(const f16x4*)&s1h_s[w][2*i][g * 16 + quad * 4];
      f16x4 sB = *(const f16x4*)&s1h_s[w][2*i + 1][g * 16 + quad * 4];
      #pragma unroll
      for (int r = 0; r < 4; ++r)
        sg[g][r] = fmaf(wb[g][r], (float)sB[r], fmaf(wa[g][r], (float)sA[r], sg[g][r]));
    }
  }
  float4 vq[2][4];
  #pragma unroll
  for (int g = 0; g < 2; ++g)
    #pragma unroll
    for (int r = 0; r < 4; ++r) vq[g][r] = vq_s[w][g * 16 + quad * 4 + r];

  float m1x[2][4], m1y[2][4], m1z[2][4];
  #pragma unroll
  for (int g = 0; g < 2; ++g)
    #pragma unroll
    for (int r = 0; r < 4; ++r) {
      m1x[g][r] = sg[g][r] * vq[g][r].x;
      m1y[g][r] = sg[g][r] * vq[g][r].y;
      m1z[g][r] = sg[g][r] * vq[g][r].z;
    }

  // ---- section 4: vs (pairs 40..47), u = sum w*v1; m1 += s2*u ----
  {
    float ux[2][4] = {{0,0,0,0},{0,0,0,0}}, uy[2][4] = {{0,0,0,0},{0,0,0,0}},
          uz[2][4] = {{0,0,0,0},{0,0,0,0}};
    #pragma unroll 1
    for (int i = 0; i < 8; ++i) {
      LOADB(40 + i)
      f32x4 wa[2], wb[2];
      chains2(af[0], af[1], b0,b1,b2,b3,b4,b5,b6,b7, bias2, wa, wb);
      #pragma unroll
      for (int g = 0; g < 2; ++g) {
        f16x4 xA = *(const f16x4*)&v1h_s[w][2*i][0][g*16 + quad*4];
        f16x4 xB = *(const f16x4*)&v1h_s[w][2*i+1][0][g*16 + quad*4];
        f16x4 yA = *(const f16x4*)&v1h_s[w][2*i][1][g*16 + quad*4];
        f16x4 yB = *(const f16x4*)&v1h_s[w][2*i+1][1][g*16 + quad*4];
        f16x4 zA = *(const f16x4*)&v1h_s[w][2*i][2][g*16 + quad*4];
        f16x4 zB = *(const f16x4*)&v1h_s[w][2*i+1][2][g*16 + quad*4];
        #pragma unroll
        for (int r = 0; r < 4; ++r) {
          ux[g][r] = fmaf(wb[g][r], (float)xB[r], fmaf(wa[g][r], (float)xA[r], ux[g][r]));
          uy[g][r] = fmaf(wb[g][r], (float)yB[r], fmaf(wa[g][r], (float)yA[r], uy[g][r]));
          uz[g][r] = fmaf(wb[g][r], (float)zB[r], fmaf(wa[g][r], (float)zA[r], uz[g][r]));
        }
      }
    }
    #pragma unroll
    for (int g = 0; g < 2; ++g)
      #pragma unroll
      for (int r = 0; r < 4; ++r) {
        m1x[g][r] = fmaf(vq[g][r].w, ux[g][r], m1x[g][r]);
        m1y[g][r] = fmaf(vq[g][r].w, uy[g][r], m1y[g][r]);
        m1z[g][r] = fmaf(vq[g][r].w, uz[g][r], m1z[g][r]);
      }
  }

  // ---- section 5: vv1 (pairs 48..55), u = sum w*v1; m1 += cross(u, v2) [INV2 folded] ----
  {
    float ux[2][4] = {{0,0,0,0},{0,0,0,0}}, uy[2][4] = {{0,0,0,0},{0,0,0,0}},
          uz[2][4] = {{0,0,0,0},{0,0,0,0}};
    #pragma unroll 1
    for (int i = 0; i < 8; ++i) {
      LOADB(48 + i)
      f32x4 wa[2], wb[2];
      chains2(af[0], af[1], b0,b1,b2,b3,b4,b5,b6,b7, bias2, wa, wb);
      #pragma unroll
      for (int g = 0; g < 2; ++g) {
        f16x4 xA = *(const f16x4*)&v1h_s[w][2*i][0][g*16 + quad*4];
        f16x4 xB = *(const f16x4*)&v1h_s[w][2*i+1][0][g*16 + quad*4];
        f16x4 yA = *(const f16x4*)&v1h_s[w][2*i][1][g*16 + quad*4];
        f16x4 yB = *(const f16x4*)&v1h_s[w][2*i+1][1][g*16 + quad*4];
        f16x4 zA = *(const f16x4*)&v1h_s[w][2*i][2][g*16 + quad*4];
        f16x4 zB = *(const f16x4*)&v1h_s[w][2*i+1][2][g*16 + quad*4];
        #pragma unroll
        for (int r = 0; r < 4; ++r) {
          ux[g][r] = fmaf(wb[g][r], (float)xB[r], fmaf(wa[g][r], (float)xA[r], ux[g][r]));
          uy[g][r] = fmaf(wb[g][r], (float)yB[r], fmaf(wa[g][r], (float)yA[r], uy[g][r]));
          uz[g][r] = fmaf(wb[g][r], (float)zB[r], fmaf(wa[g][r], (float)zA[r], uz[g][r]));
        }
      }
    }
    #pragma unroll
    for (int g = 0; g < 2; ++g)
      #pragma unroll
      for (int r = 0; r < 4; ++r) {
        m1x[g][r] = fmaf(uy[g][r], vq[g][r].z, m1x[g][r]);
        m1x[g][r] = fmaf(-uz[g][r], vq[g][r].y, m1x[g][r]);
        m1y[g][r] = fmaf(uz[g][r], vq[g][r].x, m1y[g][r]);
        m1y[g][r] = fmaf(-ux[g][r], vq[g][r].z, m1y[g][r]);
        m1z[g][r] = fmaf(ux[g][r], vq[g][r].y, m1z[g][r]);
        m1z[g][r] = fmaf(-uy[g][r], vq[g][r].x, m1z[g][r]);
      }
  }

  // ---- scatter out1 ----
  #pragma unroll
  for (int g = 0; g < 2; ++g)
    #pragma unroll
    for (int r = 0; r < 4; ++r) {
      int ge = eb + g * 16 + quad * 4 + r;
      if (ge < E) {
        float* ap = accn + (size_t)dst[ge] * 80;
        atomicAdd(ap + 32 + l16*3 + 0, m1x[g][r]);
        atomicAdd(ap + 32 + l16*3 + 1, m1y[g][r]);
        atomicAdd(ap + 32 + l16*3 + 2, m1z[g][r]);
      }
    }
}

// ---- node epilogue: 64 threads per node ----
__global__ __launch_bounds__(256) void node_kernel(
    const float* __restrict__ accn, const float* __restrict__ cnt,
    const float* __restrict__ xdst, const float* __restrict__ Wr0,
    const float* __restrict__ Wr1, float* __restrict__ out, int N)
{
  int idx = blockIdx.x * 256 + threadIdx.x;
  int n = idx >> 6, j = idx & 63;
  if (n >= N) return;
  float inv = 1.0f / fmaxf(cnt[n], 1.0f);
  const float* ap = accn + (size_t)n * 80;
  const float* xd = xdst + (size_t)n * 64;
  float* op = out + (size_t)n * 64;
  if (j < 16) {
    float s = 0.f;
    #pragma unroll
    for (int m = 0; m < 16; ++m) s = fmaf(xd[m], Wr0[m * 32 + j], s);
    op[j] = fmaxf(ap[j] * inv + 0.25f * s, 0.f);
  } else {
    int jj = j - 16;
    int o = (jj * 86) >> 8;          // jj / 3 for jj < 48
    int c = jj - o * 3;
    float tg = 0.f, v = 0.f;
    #pragma unroll
    for (int m = 0; m < 16; ++m) {
      tg = fmaf(xd[m], Wr0[m * 32 + 16 + o], tg);
      v  = fmaf(xd[16 + m * 3 + c], Wr1[m * 16 + o], v);
    }
    float g = 1.0f / (1.0f + expf(-(ap[16 + o] * inv + 0.25f * tg)));
    op[16 + jj] = (ap[32 + jj] * inv + 0.25f * v) * g;
  }
}

extern "C" void kernel_launch(void* const* d_in, const int* in_sizes, int n_in,
                              void* d_out, int out_size, void* d_ws, size_t ws_size,
                              hipStream_t stream)
{
  const int*   dst  = (const int*)d_in[0];
  const float* xsrc = (const float*)d_in[1];
  const float* xdst = (const float*)d_in[2];
  const float* sh   = (const float*)d_in[3];
  const float* ea   = (const float*)d_in[4];
  const float* We1  = (const float*)d_in[5];
  const float* be1  = (const float*)d_in[6];
  const float* We2  = (const float*)d_in[7];
  const float* be2  = (const float*)d_in[8];
  const float* Wr0  = (const float*)d_in[9];
  const float* Wr1  = (const float*)d_in[10];
  const int E = in_sizes[0];
  const int N = in_sizes[2] / 64;

  char* ws = (char*)d_ws;
  _Float16* we2h = (_Float16*)ws;                           // 458,752 B
  unsigned short* we1x = (unsigned short*)(ws + 458752);    //  16,384 B
  float* be2p = (float*)(ws + 475136);                      //   7,424 B
  float* accn = (float*)(ws + 482560);                      // N*80*4
  float* cnt  = (float*)(ws + 482560 + (size_t)N * 320);    // N*4

  hipMemsetAsync(accn, 0, (size_t)N * 320 + (size_t)N * 4, stream);

  prep_kernel<<<(30976 + 255) / 256, 256, 0, stream>>>(We1, We2, be2, we1x, we2h, be2p);
  edge_kernel<<<(E + 63) / 64, 128, 0, stream>>>(ea, xsrc, sh, dst, be1,
      we1x, we2h, be2p, accn, cnt, E);
  node_kernel<<<((size_t)N * 64 + 255) / 256, 256, 0, stream>>>(accn, cnt, xdst, Wr0, Wr1,
      (float*)d_out, N);
}

// Round 9
// 232.621 us; speedup vs baseline: 1.1685x; 1.0279x over previous
//
#include <hip/hip_runtime.h>
#include <math.h>

#define WNUM 1792
#define HID 128

#define INV3C 0.5773502691896258f
#define INV2C 0.7071067811865476f
#define A0C   0.17677669529663687f   /* 1/sqrt(32) */
#define A1C   0.14433756729740643f   /* 1/sqrt(48) */

typedef short bf8 __attribute__((ext_vector_type(8)));
typedef _Float16 f16x8 __attribute__((ext_vector_type(8)));
typedef _Float16 f16x4 __attribute__((ext_vector_type(4)));
typedef float f32x4 __attribute__((ext_vector_type(4)));

__device__ inline unsigned short f2bf(float f) {
  union { float f; unsigned u; } v; v.f = f;
  unsigned r = v.u + 0x7FFFu + ((v.u >> 16) & 1u);   // RNE
  return (unsigned short)(r >> 16);
}
__device__ inline float bf2f(unsigned short h) {
  union { unsigned u; float f; } v; v.u = ((unsigned)h) << 16;
  return v.f;
}
__device__ inline float wscale(int t) {   // section constants folded into weights+biases
  if (t < 32) return A0C;
  if (t < 64) return A0C * INV3C;
  if (t < 96) return A1C;
  return A1C * INV2C;
}

// ---- prep: coalesced-write weight staging (layouts unchanged from R7/R8) ----
__global__ __launch_bounds__(256) void prep_kernel(
    const float* __restrict__ We1, const float* __restrict__ We2,
    const float* __restrict__ be2,
    unsigned short* __restrict__ we1x, _Float16* __restrict__ we2h,
    float* __restrict__ be2p)
{
  int i = blockIdx.x * 256 + threadIdx.x;
  if (i < 28672) {                       // we2h: one thread per (t, c, lane) = 112*4*64
    int t = i >> 8, c = (i >> 6) & 3, lane = i & 63;
    int quad = lane >> 4, l15 = lane & 15;
    int col = t * 16 + l15;
    float sc = wscale(t);
    f16x8 v;
    #pragma unroll
    for (int j = 0; j < 8; ++j) {
      int k = c * 32 + quad * 8 + j;
      v[j] = (_Float16)(We2[(size_t)k * WNUM + col] * sc);
    }
    *(f16x8*)(we2h + (size_t)t * 2048 + c * 512 + lane * 8) = v;
  } else if (i < 29184) {                // we1x: one thread per (c1, lane) = 512
    int q = i - 28672;
    int c1 = q >> 6, lane = q & 63;
    int quad = lane >> 4, l15 = lane & 15;
    int col = c1 * 16 + l15;
    bf8 hh, ll;
    #pragma unroll
    for (int j = 0; j < 8; ++j) {
      int k = quad * 8 + j;
      float v = We1[k * HID + col];
      unsigned short hi = f2bf(v);
      hh[j] = (short)hi;
      ll[j] = (short)f2bf(v - bf2f(hi));
    }
    *(bf8*)(we1x + c1 * 1024 + lane * 8) = hh;
    *(bf8*)(we1x + c1 * 1024 + 512 + lane * 8) = ll;
  } else if (i < 30976) {                // be2p: 1792 entries
    int q = i - 29184;                   // q = t*16 + l16
    int t = q >> 4, l16 = q & 15;
    be2p[(t >> 1) * 32 + l16 * 2 + (t & 1)] = be2[q] * wscale(t);
  }
}

// 16 MFMAs: two edge-groups x two tiles, 4 independent chains of 4
__device__ inline void chains2(const f16x8* a0, const f16x8* a1,
    f16x8 b0, f16x8 b1, f16x8 b2, f16x8 b3,
    f16x8 b4, f16x8 b5, f16x8 b6, f16x8 b7,
    float2 bias, f32x4* wa, f32x4* wb)
{
  f32x4 ca0 = {bias.x, bias.x, bias.x, bias.x};
  f32x4 cb0 = {bias.y, bias.y, bias.y, bias.y};
  f32x4 ca1 = ca0, cb1 = cb0;
  ca0 = __builtin_amdgcn_mfma_f32_16x16x32_f16(a0[0], b0, ca0, 0, 0, 0);
  cb0 = __builtin_amdgcn_mfma_f32_16x16x32_f16(a0[0], b4, cb0, 0, 0, 0);
  ca1 = __builtin_amdgcn_mfma_f32_16x16x32_f16(a1[0], b0, ca1, 0, 0, 0);
  cb1 = __builtin_amdgcn_mfma_f32_16x16x32_f16(a1[0], b4, cb1, 0, 0, 0);
  ca0 = __builtin_amdgcn_mfma_f32_16x16x32_f16(a0[1], b1, ca0, 0, 0, 0);
  cb0 = __builtin_amdgcn_mfma_f32_16x16x32_f16(a0[1], b5, cb0, 0, 0, 0);
  ca1 = __builtin_amdgcn_mfma_f32_16x16x32_f16(a1[1], b1, ca1, 0, 0, 0);
  cb1 = __builtin_amdgcn_mfma_f32_16x16x32_f16(a1[1], b5, cb1, 0, 0, 0);
  ca0 = __builtin_amdgcn_mfma_f32_16x16x32_f16(a0[2], b2, ca0, 0, 0, 0);
  cb0 = __builtin_amdgcn_mfma_f32_16x16x32_f16(a0[2], b6, cb0, 0, 0, 0);
  ca1 = __builtin_amdgcn_mfma_f32_16x16x32_f16(a1[2], b2, ca1, 0, 0, 0);
  cb1 = __builtin_amdgcn_mfma_f32_16x16x32_f16(a1[2], b6, cb1, 0, 0, 0);
  ca0 = __builtin_amdgcn_mfma_f32_16x16x32_f16(a0[3], b3, ca0, 0, 0, 0);
  cb0 = __builtin_amdgcn_mfma_f32_16x16x32_f16(a0[3], b7, cb0, 0, 0, 0);
  ca1 = __builtin_amdgcn_mfma_f32_16x16x32_f16(a1[3], b3, ca1, 0, 0, 0);
  cb1 = __builtin_amdgcn_mfma_f32_16x16x32_f16(a1[3], b7, cb1, 0, 0, 0);
  wa[0] = ca0; wb[0] = cb0; wa[1] = ca1; wb[1] = cb1;
}

// read the 8 B-fragments of the current pair from LDS (ds_read_b128 x8)
#define LOADB_LDS(BASE) \
  f16x8 b0 = *(const f16x8*)((BASE)); \
  f16x8 b1 = *(const f16x8*)((BASE) + 512); \
  f16x8 b2 = *(const f16x8*)((BASE) + 1024); \
  f16x8 b3 = *(const f16x8*)((BASE) + 1536); \
  f16x8 b4 = *(const f16x8*)((BASE) + 2048); \
  f16x8 b5 = *(const f16x8*)((BASE) + 2560); \
  f16x8 b6 = *(const f16x8*)((BASE) + 3072); \
  f16x8 b7 = *(const f16x8*)((BASE) + 3584);

// ---- fused edge kernel: 256 threads = 4 waves x 32 edges; B staged in LDS dbuf ----
__global__ __launch_bounds__(256, 2) void edge_kernel(
    const float* __restrict__ ea, const float* __restrict__ xsrc,
    const float* __restrict__ sh, const int* __restrict__ dst,
    const float* __restrict__ be1,
    const unsigned short* __restrict__ we1x, const _Float16* __restrict__ we2h,
    const float* __restrict__ be2p,
    float* __restrict__ accn, float* __restrict__ cnt, int E)
{
  const int lane = threadIdx.x & 63;
  const int w    = threadIdx.x >> 6;       // 0..3
  const int quad = lane >> 4;
  const int l16  = lane & 15;
  const int eb   = (blockIdx.x * 4 + w) * 32;

  __shared__ _Float16 Bsm[2][4096];           // 16 KB  B-pair double buffer
  __shared__ _Float16 h_s[4][32][136];        // 34.8 KB
  __shared__ _Float16 fss_s[4][16][32];       // 4 KB  s1*s2
  __shared__ _Float16 fvv_s[4][16][32];       // 4 KB  v1.v2
  __shared__ _Float16 s1h_s[4][16][32];       // 4 KB
  __shared__ _Float16 v1h_s[4][16][3][32];    // 12 KB
  __shared__ float4 vq_s[4][32];              // 2 KB  {v2x,v2y,v2z,s2}

  // wave-cooperative stage of pair p into ldsbuf (2 x 1KB chunks per wave)
  #define STAGEB(ldsbuf, p) { \
    const _Float16* gsrc_ = we2h + (size_t)(p) * 4096; \
    __builtin_amdgcn_global_load_lds( \
      (const __attribute__((address_space(1))) void*)(gsrc_ + (w * 2) * 512 + lane * 8), \
      (__attribute__((address_space(3))) void*)((ldsbuf) + (w * 2) * 512), 16, 0, 0); \
    __builtin_amdgcn_global_load_lds( \
      (const __attribute__((address_space(1))) void*)(gsrc_ + (w * 2 + 1) * 512 + lane * 8), \
      (__attribute__((address_space(3))) void*)((ldsbuf) + (w * 2 + 1) * 512), 16, 0, 0); \
  }

  // ---- stage per-edge factors (lane -> e2 = lane>>1, m-half = lane&1) ----
  {
    int e2 = lane >> 1, mg = lane & 1;
    int ge = eb + e2;
    if (ge < E) {
      const float* xp = xsrc + (size_t)ge * 64;
      float4 sq0 = *(const float4*)(xp + mg * 8);
      float4 sq1 = *(const float4*)(xp + mg * 8 + 4);
      float s1a[8] = {sq0.x,sq0.y,sq0.z,sq0.w,sq1.x,sq1.y,sq1.z,sq1.w};
      const float* vp = xp + 16 + mg * 24;
      float la[24];
      #pragma unroll
      for (int qv = 0; qv < 6; ++qv) {
        float4 t = *(const float4*)(vp + qv * 4);
        la[qv*4+0] = t.x; la[qv*4+1] = t.y; la[qv*4+2] = t.z; la[qv*4+3] = t.w;
      }
      float4 shq = *(const float4*)(sh + (size_t)ge * 4);
      float s2 = shq.x, v2x = shq.y, v2y = shq.z, v2z = shq.w;
      #pragma unroll
      for (int mi = 0; mi < 8; ++mi) {
        int m = mg * 8 + mi;
        float v1x = la[mi*3], v1y = la[mi*3+1], v1z = la[mi*3+2];
        fss_s[w][m][e2] = (_Float16)(s1a[mi] * s2);
        fvv_s[w][m][e2] = (_Float16)(v1x*v2x + v1y*v2y + v1z*v2z);
        s1h_s[w][m][e2] = (_Float16)s1a[mi];
        v1h_s[w][m][0][e2] = (_Float16)v1x;
        v1h_s[w][m][1][e2] = (_Float16)v1y;
        v1h_s[w][m][2][e2] = (_Float16)v1z;
      }
      if (mg == 0) vq_s[w][e2] = make_float4(v2x, v2y, v2z, s2);
    } else {
      #pragma unroll
      for (int mi = 0; mi < 8; ++mi) {
        int m = mg * 8 + mi;
        fss_s[w][m][e2] = (_Float16)0.f;
        fvv_s[w][m][e2] = (_Float16)0.f;
        s1h_s[w][m][e2] = (_Float16)0.f;
        v1h_s[w][m][0][e2] = (_Float16)0.f;
        v1h_s[w][m][1][e2] = (_Float16)0.f;
        v1h_s[w][m][2][e2] = (_Float16)0.f;
      }
      if (mg == 0) vq_s[w][e2] = make_float4(0,0,0,0);
    }
  }

  // ---- layer 1: two 16-edge groups per wave, B-fragments shared across groups ----
  {
    bf8 ah[2], al[2];
    #pragma unroll
    for (int g = 0; g < 2; ++g) {
      int gea = eb + g * 16 + l16; if (gea > E - 1) gea = E - 1;
      if (gea < 0) gea = 0;
      const float* ep = ea + (size_t)gea * 32 + quad * 8;
      float4 p0 = *(const float4*)ep;
      float4 p1 = *(const float4*)(ep + 4);
      float pv[8] = {p0.x,p0.y,p0.z,p0.w,p1.x,p1.y,p1.z,p1.w};
      #pragma unroll
      for (int j = 0; j < 8; ++j) {
        unsigned short hi = f2bf(pv[j]);
        ah[g][j] = (short)hi;
        al[g][j] = (short)f2bf(pv[j] - bf2f(hi));
      }
    }
    const unsigned short* wb1 = we1x + lane * 8;
    #pragma unroll 2
    for (int c = 0; c < 8; ++c) {
      bf8 bh = *(const bf8*)(wb1 + c * 1024);
      bf8 bl = *(const bf8*)(wb1 + c * 1024 + 512);
      float bias = be1[c * 16 + l16];
      #pragma unroll
      for (int g = 0; g < 2; ++g) {
        f32x4 hc = {bias, bias, bias, bias};
        hc = __builtin_amdgcn_mfma_f32_16x16x32_bf16(al[g], bh, hc, 0, 0, 0);
        hc = __builtin_amdgcn_mfma_f32_16x16x32_bf16(ah[g], bl, hc, 0, 0, 0);
        hc = __builtin_amdgcn_mfma_f32_16x16x32_bf16(ah[g], bh, hc, 0, 0, 0);
        #pragma unroll
        for (int r = 0; r < 4; ++r)
          h_s[w][g * 16 + quad * 4 + r][c * 16 + l16] = (_Float16)fmaxf(hc[r], 0.f);
      }
    }
  }

  // stage pair 0 while the h/factors barrier drains
  STAGEB(&Bsm[0][0], 0)
  __syncthreads();

  // ---- A fragments for both groups ----
  f16x8 af[2][4];
  #pragma unroll
  for (int g = 0; g < 2; ++g)
    #pragma unroll
    for (int ch = 0; ch < 4; ++ch)
      af[g][ch] = *(const f16x8*)&h_s[w][g * 16 + l16][ch * 32 + quad * 8];

  const float* bp = be2p + l16 * 2;

  float m0a[2][4] = {{0,0,0,0},{0,0,0,0}}, m0b[2][4] = {{0,0,0,0},{0,0,0,0}};
  int p = 0;

  // ---- section 1: ss (pairs 0..15), out0 += w * (s1*s2) ----
  #pragma unroll 1
  for (int i = 0; i < 16; ++i) {
    STAGEB(&Bsm[(p + 1) & 1][0], p + 1)
    const _Float16* bL = &Bsm[p & 1][lane * 8];
    LOADB_LDS(bL)
    float2 bias2 = *(const float2*)(bp + p * 32);
    f32x4 wa[2], wb[2];
    chains2(af[0], af[1], b0,b1,b2,b3,b4,b5,b6,b7, bias2, wa, wb);
    #pragma unroll
    for (int g = 0; g < 2; ++g) {
      f16x4 fv = *(const f16x4*)&fss_s[w][i][g * 16 + quad * 4];
      #pragma unroll
      for (int r = 0; r < 4; ++r) {
        float f = (float)fv[r];
        m0a[g][r] = fmaf(wa[g][r], f, m0a[g][r]);
        m0b[g][r] = fmaf(wb[g][r], f, m0b[g][r]);
      }
    }
    __syncthreads();
    ++p;
  }

  // ---- section 2: vv0 (pairs 16..31), out0 += w * (v1.v2) [INV3 folded] ----
  #pragma unroll 1
  for (int i = 0; i < 16; ++i) {
    STAGEB(&Bsm[(p + 1) & 1][0], p + 1)
    const _Float16* bL = &Bsm[p & 1][lane * 8];
    LOADB_LDS(bL)
    float2 bias2 = *(const float2*)(bp + p * 32);
    f32x4 wa[2], wb[2];
    chains2(af[0], af[1], b0,b1,b2,b3,b4,b5,b6,b7, bias2, wa, wb);
    #pragma unroll
    for (int g = 0; g < 2; ++g) {
      f16x4 fv = *(const f16x4*)&fvv_s[w][i][g * 16 + quad * 4];
      #pragma unroll
      for (int r = 0; r < 4; ++r) {
        float f = (float)fv[r];
        m0a[g][r] = fmaf(wa[g][r], f, m0a[g][r]);
        m0b[g][r] = fmaf(wb[g][r], f, m0b[g][r]);
      }
    }
    __syncthreads();
    ++p;
  }

  // ---- scatter out0 now (frees registers) + counts ----
  #pragma unroll
  for (int g = 0; g < 2; ++g)
    #pragma unroll
    for (int r = 0; r < 4; ++r) {
      int ge = eb + g * 16 + quad * 4 + r;
      if (ge < E) {
        float* ap = accn + (size_t)dst[ge] * 80;
        atomicAdd(ap + l16,      m0a[g][r]);
        atomicAdd(ap + 16 + l16, m0b[g][r]);
      }
    }
  if (lane < 32) {
    int ge = eb + lane;
    if (ge < E) atomicAdd(cnt + dst[ge], 1.0f);
  }

  // ---- section 3: sv (pairs 32..39), sigma = sum w*s1; m1 = sigma*v2 ----
  float sg[2][4] = {{0,0,0,0},{0,0,0,0}};
  #pragma unroll 1
  for (int i = 0; i < 8; ++i) {
    STAGEB(&Bsm[(p + 1) & 1][0], p + 1)
    const _Float16* bL = &Bsm[p & 1][lane * 8];
    LOADB_LDS(bL)
    float2 bias2 = *(const float2*)(bp + p * 32);
    f32x4 wa[2], wb[2];
    chains2(af[0], af[1], b0,b1,b2,b3,b4,b5,b6,b7, bias2, wa, wb);
    #pragma unroll
    for (int g = 0; g < 2; ++g) {
      f16x4 sA = *(const f16x4*)&s1h_s[w][2*i][g * 16 + quad * 4];
      f16x4 sB = *(const f16x4*)&s1h_s[w][2*i + 1][g * 16 + quad * 4];
      #pragma unroll
      for (int r = 0; r < 4; ++r)
        sg[g][r] = fmaf(wb[g][r], (float)sB[r], fmaf(wa[g][r], (float)sA[r], sg[g][r]));
    }
    __syncthreads();
    ++p;
  }
  float4 vq[2][4];
  #pragma unroll
  for (int g = 0; g < 2; ++g)
    #pragma unroll
    for (int r = 0; r < 4; ++r) vq[g][r] = vq_s[w][g * 16 + quad * 4 + r];

  float m1x[2][4], m1y[2][4], m1z[2][4];
  #pragma unroll
  for (int g = 0; g < 2; ++g)
    #pragma unroll
    for (int r = 0; r < 4; ++r) {
      m1x[g][r] = sg[g][r] * vq[g][r].x;
      m1y[g][r] = sg[g][r] * vq[g][r].y;
      m1z[g][r] = sg[g][r] * vq[g][r].z;
    }

  // ---- section 4: vs (pairs 40..47), u = sum w*v1; m1 += s2*u ----
  {
    float ux[2][4] = {{0,0,0,0},{0,0,0,0}}, uy[2][4] = {{0,0,0,0},{0,0,0,0}},
          uz[2][4] = {{0,0,0,0},{0,0,0,0}};
    #pragma unroll 1
    for (int i = 0; i < 8; ++i) {
      STAGEB(&Bsm[(p + 1) & 1][0], p + 1)
      const _Float16* bL = &Bsm[p & 1][lane * 8];
      LOADB_LDS(bL)
      float2 bias2 = *(const float2*)(bp + p * 32);
      f32x4 wa[2], wb[2];
      chains2(af[0], af[1], b0,b1,b2,b3,b4,b5,b6,b7, bias2, wa, wb);
      #pragma unroll
      for (int g = 0; g < 2; ++g) {
        f16x4 xA = *(const f16x4*)&v1h_s[w][2*i][0][g*16 + quad*4];
        f16x4 xB = *(const f16x4*)&v1h_s[w][2*i+1][0][g*16 + quad*4];
        f16x4 yA = *(const f16x4*)&v1h_s[w][2*i][1][g*16 + quad*4];
        f16x4 yB = *(const f16x4*)&v1h_s[w][2*i+1][1][g*16 + quad*4];
        f16x4 zA = *(const f16x4*)&v1h_s[w][2*i][2][g*16 + quad*4];
        f16x4 zB = *(const f16x4*)&v1h_s[w][2*i+1][2][g*16 + quad*4];
        #pragma unroll
        for (int r = 0; r < 4; ++r) {
          ux[g][r] = fmaf(wb[g][r], (float)xB[r], fmaf(wa[g][r], (float)xA[r], ux[g][r]));
          uy[g][r] = fmaf(wb[g][r], (float)yB[r], fmaf(wa[g][r], (float)yA[r], uy[g][r]));
          uz[g][r] = fmaf(wb[g][r], (float)zB[r], fmaf(wa[g][r], (float)zA[r], uz[g][r]));
        }
      }
      __syncthreads();
      ++p;
    }
    #pragma unroll
    for (int g = 0; g < 2; ++g)
      #pragma unroll
      for (int r = 0; r < 4; ++r) {
        m1x[g][r] = fmaf(vq[g][r].w, ux[g][r], m1x[g][r]);
        m1y[g][r] = fmaf(vq[g][r].w, uy[g][r], m1y[g][r]);
        m1z[g][r] = fmaf(vq[g][r].w, uz[g][r], m1z[g][r]);
      }
  }

  // ---- section 5: vv1 (pairs 48..55), u = sum w*v1; m1 += cross(u, v2) [INV2 folded] ----
  {
    float ux[2][4] = {{0,0,0,0},{0,0,0,0}}, uy[2][4] = {{0,0,0,0},{0,0,0,0}},
          uz[2][4] = {{0,0,0,0},{0,0,0,0}};
    #pragma unroll 1
    for (int i = 0; i < 8; ++i) {
      if (p + 1 < 56) STAGEB(&Bsm[(p + 1) & 1][0], p + 1)
      const _Float16* bL = &Bsm[p & 1][lane * 8];
      LOADB_LDS(bL)
      float2 bias2 = *(const float2*)(bp + p * 32);
      f32x4 wa[2], wb[2];
      chains2(af[0], af[1], b0,b1,b2,b3,b4,b5,b6,b7, bias2, wa, wb);
      #pragma unroll
      for (int g = 0; g < 2; ++g) {
        f16x4 xA = *(const f16x4*)&v1h_s[w][2*i][0][g*16 + quad*4];
        f16x4 xB = *(const f16x4*)&v1h_s[w][2*i+1][0][g*16 + quad*4];
        f16x4 yA = *(const f16x4*)&v1h_s[w][2*i][1][g*16 + quad*4];
        f16x4 yB = *(const f16x4*)&v1h_s[w][2*i+1][1][g*16 + quad*4];
        f16x4 zA = *(const f16x4*)&v1h_s[w][2*i][2][g*16 + quad*4];
        f16x4 zB = *(const f16x4*)&v1h_s[w][2*i+1][2][g*16 + quad*4];
        #pragma unroll
        for (int r = 0; r < 4; ++r) {
          ux[g][r] = fmaf(wb[g][r], (float)xB[r], fmaf(wa[g][r], (float)xA[r], ux[g][r]));
          uy[g][r] = fmaf(wb[g][r], (float)yB[r], fmaf(wa[g][r], (float)yA[r], uy[g][r]));
          uz[g][r] = fmaf(wb[g][r], (float)zB[r], fmaf(wa[g][r], (float)zA[r], uz[g][r]));
        }
      }
      __syncthreads();
      ++p;
    }
    #pragma unroll
    for (int g = 0; g < 2; ++g)
      #pragma unroll
      for (int r = 0; r < 4; ++r) {
        m1x[g][r] = fmaf(uy[g][r], vq[g][r].z, m1x[g][r]);
        m1x[g][r] = fmaf(-uz[g][r], vq[g][r].y, m1x[g][r]);
        m1y[g][r] = fmaf(uz[g][r], vq[g][r].x, m1y[g][r]);
        m1y[g][r] = fmaf(-ux[g][r], vq[g][r].z, m1y[g][r]);
        m1z[g][r] = fmaf(ux[g][r], vq[g][r].y, m1z[g][r]);
        m1z[g][r] = fmaf(-uy[g][r], vq[g][r].x, m1z[g][r]);
      }
  }

  // ---- scatter out1 ----
  #pragma unroll
  for (int g = 0; g < 2; ++g)
    #pragma unroll
    for (int r = 0; r < 4; ++r) {
      int ge = eb + g * 16 + quad * 4 + r;
      if (ge < E) {
        float* ap = accn + (size_t)dst[ge] * 80;
        atomicAdd(ap + 32 + l16*3 + 0, m1x[g][r]);
        atomicAdd(ap + 32 + l16*3 + 1, m1y[g][r]);
        atomicAdd(ap + 32 + l16*3 + 2, m1z[g][r]);
      }
    }
  #undef STAGEB
}

// ---- node epilogue: 64 threads per node ----
__global__ __launch_bounds__(256) void node_kernel(
    const float* __restrict__ accn, const float* __restrict__ cnt,
    const float* __restrict__ xdst, const float* __restrict__ Wr0,
    const float* __restrict__ Wr1, float* __restrict__ out, int N)
{
  int idx = blockIdx.x * 256 + threadIdx.x;
  int n = idx >> 6, j = idx & 63;
  if (n >= N) return;
  float inv = 1.0f / fmaxf(cnt[n], 1.0f);
  const float* ap = accn + (size_t)n * 80;
  const float* xd = xdst + (size_t)n * 64;
  float* op = out + (size_t)n * 64;
  if (j < 16) {
    float s = 0.f;
    #pragma unroll
    for (int m = 0; m < 16; ++m) s = fmaf(xd[m], Wr0[m * 32 + j], s);
    op[j] = fmaxf(ap[j] * inv + 0.25f * s, 0.f);
  } else {
    int jj = j - 16;
    int o = (jj * 86) >> 8;          // jj / 3 for jj < 48
    int c = jj - o * 3;
    float tg = 0.f, v = 0.f;
    #pragma unroll
    for (int m = 0; m < 16; ++m) {
      tg = fmaf(xd[m], Wr0[m * 32 + 16 + o], tg);
      v  = fmaf(xd[16 + m * 3 + c], Wr1[m * 16 + o], v);
    }
    float g = 1.0f / (1.0f + expf(-(ap[16 + o] * inv + 0.25f * tg)));
    op[16 + jj] = (ap[32 + jj] * inv + 0.25f * v) * g;
  }
}

extern "C" void kernel_launch(void* const* d_in, const int* in_sizes, int n_in,
                              void* d_out, int out_size, void* d_ws, size_t ws_size,
                              hipStream_t stream)
{
  const int*   dst  = (const int*)d_in[0];
  const float* xsrc = (const float*)d_in[1];
  const float* xdst = (const float*)d_in[2];
  const float* sh   = (const float*)d_in[3];
  const float* ea   = (const float*)d_in[4];
  const float* We1  = (const float*)d_in[5];
  const float* be1  = (const float*)d_in[6];
  const float* We2  = (const float*)d_in[7];
  const float* be2  = (const float*)d_in[8];
  const float* Wr0  = (const float*)d_in[9];
  const float* Wr1  = (const float*)d_in[10];
  const int E = in_sizes[0];
  const int N = in_sizes[2] / 64;

  char* ws = (char*)d_ws;
  _Float16* we2h = (_Float16*)ws;                           // 458,752 B
  unsigned short* we1x = (unsigned short*)(ws + 458752);    //  16,384 B
  float* be2p = (float*)(ws + 475136);                      //   7,424 B
  float* accn = (float*)(ws + 482560);                      // N*80*4
  float* cnt  = (float*)(ws + 482560 + (size_t)N * 320);    // N*4

  hipMemsetAsync(accn, 0, (size_t)N * 320 + (size_t)N * 4, stream);

  prep_kernel<<<(30976 + 255) / 256, 256, 0, stream>>>(We1, We2, be2, we1x, we2h, be2p);
  edge_kernel<<<(E + 127) / 128, 256, 0, stream>>>(ea, xsrc, sh, dst, be1,
      we1x, we2h, be2p, accn, cnt, E);
  node_kernel<<<((size_t)N * 64 + 255) / 256, 256, 0, stream>>>(accn, cnt, xdst, Wr0, Wr1,
      (float*)d_out, N);
}

// Round 10
// 204.191 us; speedup vs baseline: 1.3312x; 1.1392x over previous
//
#include <hip/hip_runtime.h>
#include <math.h>

#define WNUM 1792
#define HID 128

#define INV3C 0.5773502691896258f
#define INV2C 0.7071067811865476f
#define A0C   0.17677669529663687f   /* 1/sqrt(32) */
#define A1C   0.14433756729740643f   /* 1/sqrt(48) */
#define MAXDEG 64

typedef short bf8 __attribute__((ext_vector_type(8)));
typedef _Float16 f16x8 __attribute__((ext_vector_type(8)));
typedef _Float16 f16x4 __attribute__((ext_vector_type(4)));
typedef float f32x4 __attribute__((ext_vector_type(4)));

__device__ inline unsigned short f2bf(float f) {
  union { float f; unsigned u; } v; v.f = f;
  unsigned r = v.u + 0x7FFFu + ((v.u >> 16) & 1u);   // RNE
  return (unsigned short)(r >> 16);
}
__device__ inline float bf2f(unsigned short h) {
  union { unsigned u; float f; } v; v.u = ((unsigned)h) << 16;
  return v.f;
}
__device__ inline float wscale(int t) {
  if (t < 32) return A0C;
  if (t < 64) return A0C * INV3C;
  if (t < 96) return A1C;
  return A1C * INV2C;
}

// ---- prep: weight staging + cnt zeroing (layouts unchanged from R9) ----
__global__ __launch_bounds__(256) void prep_kernel(
    const float* __restrict__ We1, const float* __restrict__ We2,
    const float* __restrict__ be2,
    unsigned short* __restrict__ we1x, _Float16* __restrict__ we2h,
    float* __restrict__ be2p, int* __restrict__ cntp, int N)
{
  int i = blockIdx.x * 256 + threadIdx.x;
  if (i < 28672) {
    int t = i >> 8, c = (i >> 6) & 3, lane = i & 63;
    int quad = lane >> 4, l15 = lane & 15;
    int col = t * 16 + l15;
    float sc = wscale(t);
    f16x8 v;
    #pragma unroll
    for (int j = 0; j < 8; ++j) {
      int k = c * 32 + quad * 8 + j;
      v[j] = (_Float16)(We2[(size_t)k * WNUM + col] * sc);
    }
    *(f16x8*)(we2h + (size_t)t * 2048 + c * 512 + lane * 8) = v;
  } else if (i < 29184) {
    int q = i - 28672;
    int c1 = q >> 6, lane = q & 63;
    int quad = lane >> 4, l15 = lane & 15;
    int col = c1 * 16 + l15;
    bf8 hh, ll;
    #pragma unroll
    for (int j = 0; j < 8; ++j) {
      int k = quad * 8 + j;
      float v = We1[k * HID + col];
      unsigned short hi = f2bf(v);
      hh[j] = (short)hi;
      ll[j] = (short)f2bf(v - bf2f(hi));
    }
    *(bf8*)(we1x + c1 * 1024 + lane * 8) = hh;
    *(bf8*)(we1x + c1 * 1024 + 512 + lane * 8) = ll;
  } else if (i < 30976) {
    int q = i - 29184;
    int t = q >> 4, l16 = q & 15;
    be2p[(t >> 1) * 32 + l16 * 2 + (t & 1)] = be2[q] * wscale(t);
  } else if (i < 30976 + N) {
    cntp[i - 30976] = 0;
  }
}

__device__ inline void chains2(const f16x8* a0, const f16x8* a1,
    f16x8 b0, f16x8 b1, f16x8 b2, f16x8 b3,
    f16x8 b4, f16x8 b5, f16x8 b6, f16x8 b7,
    float2 bias, f32x4* wa, f32x4* wb)
{
  f32x4 ca0 = {bias.x, bias.x, bias.x, bias.x};
  f32x4 cb0 = {bias.y, bias.y, bias.y, bias.y};
  f32x4 ca1 = ca0, cb1 = cb0;
  ca0 = __builtin_amdgcn_mfma_f32_16x16x32_f16(a0[0], b0, ca0, 0, 0, 0);
  cb0 = __builtin_amdgcn_mfma_f32_16x16x32_f16(a0[0], b4, cb0, 0, 0, 0);
  ca1 = __builtin_amdgcn_mfma_f32_16x16x32_f16(a1[0], b0, ca1, 0, 0, 0);
  cb1 = __builtin_amdgcn_mfma_f32_16x16x32_f16(a1[0], b4, cb1, 0, 0, 0);
  ca0 = __builtin_amdgcn_mfma_f32_16x16x32_f16(a0[1], b1, ca0, 0, 0, 0);
  cb0 = __builtin_amdgcn_mfma_f32_16x16x32_f16(a0[1], b5, cb0, 0, 0, 0);
  ca1 = __builtin_amdgcn_mfma_f32_16x16x32_f16(a1[1], b1, ca1, 0, 0, 0);
  cb1 = __builtin_amdgcn_mfma_f32_16x16x32_f16(a1[1], b5, cb1, 0, 0, 0);
  ca0 = __builtin_amdgcn_mfma_f32_16x16x32_f16(a0[2], b2, ca0, 0, 0, 0);
  cb0 = __builtin_amdgcn_mfma_f32_16x16x32_f16(a0[2], b6, cb0, 0, 0, 0);
  ca1 = __builtin_amdgcn_mfma_f32_16x16x32_f16(a1[2], b2, ca1, 0, 0, 0);
  cb1 = __builtin_amdgcn_mfma_f32_16x16x32_f16(a1[2], b6, cb1, 0, 0, 0);
  ca0 = __builtin_amdgcn_mfma_f32_16x16x32_f16(a0[3], b3, ca0, 0, 0, 0);
  cb0 = __builtin_amdgcn_mfma_f32_16x16x32_f16(a0[3], b7, cb0, 0, 0, 0);
  ca1 = __builtin_amdgcn_mfma_f32_16x16x32_f16(a1[3], b3, ca1, 0, 0, 0);
  cb1 = __builtin_amdgcn_mfma_f32_16x16x32_f16(a1[3], b7, cb1, 0, 0, 0);
  wa[0] = ca0; wb[0] = cb0; wa[1] = ca1; wb[1] = cb1;
}

#define LOADB_LDS(BASE) \
  f16x8 b0 = *(const f16x8*)((BASE)); \
  f16x8 b1 = *(const f16x8*)((BASE) + 512); \
  f16x8 b2 = *(const f16x8*)((BASE) + 1024); \
  f16x8 b3 = *(const f16x8*)((BASE) + 1536); \
  f16x8 b4 = *(const f16x8*)((BASE) + 2048); \
  f16x8 b5 = *(const f16x8*)((BASE) + 2560); \
  f16x8 b6 = *(const f16x8*)((BASE) + 3072); \
  f16x8 b7 = *(const f16x8*)((BASE) + 3584);

// ---- fused edge kernel: 256 threads = 4 waves x 32 edges; B staged in LDS dbuf ----
// MSG=true: write dense msg rows + slot-fill (1 atomic/edge).  MSG=false: R9 atomic scatter.
template <bool MSG>
__global__ __launch_bounds__(256, 2) void edge_kernel(
    const float* __restrict__ ea, const float* __restrict__ xsrc,
    const float* __restrict__ sh, const int* __restrict__ dst,
    const float* __restrict__ be1,
    const unsigned short* __restrict__ we1x, const _Float16* __restrict__ we2h,
    const float* __restrict__ be2p,
    float* __restrict__ outp,       // msg (MSG) or accn (!MSG)
    int* __restrict__ eidx, int* __restrict__ cntp, int E)
{
  const int lane = threadIdx.x & 63;
  const int w    = threadIdx.x >> 6;
  const int quad = lane >> 4;
  const int l16  = lane & 15;
  const int eb   = (blockIdx.x * 4 + w) * 32;

  __shared__ _Float16 Bsm[2][4096];
  __shared__ _Float16 h_s[4][32][136];
  __shared__ _Float16 fss_s[4][16][32];
  __shared__ _Float16 fvv_s[4][16][32];
  __shared__ _Float16 s1h_s[4][16][32];
  __shared__ _Float16 v1h_s[4][16][3][32];
  __shared__ float4 vq_s[4][32];

  #define STAGEB(ldsbuf, p) { \
    const _Float16* gsrc_ = we2h + (size_t)(p) * 4096; \
    __builtin_amdgcn_global_load_lds( \
      (const __attribute__((address_space(1))) void*)(gsrc_ + (w * 2) * 512 + lane * 8), \
      (__attribute__((address_space(3))) void*)((ldsbuf) + (w * 2) * 512), 16, 0, 0); \
    __builtin_amdgcn_global_load_lds( \
      (const __attribute__((address_space(1))) void*)(gsrc_ + (w * 2 + 1) * 512 + lane * 8), \
      (__attribute__((address_space(3))) void*)((ldsbuf) + (w * 2 + 1) * 512), 16, 0, 0); \
  }

  // slot-fill / count early (overlaps with everything)
  if (lane < 32) {
    int ge = eb + lane;
    if (ge < E) {
      int node = dst[ge];
      int pos = atomicAdd(cntp + node, 1);
      if (MSG) { if (pos < MAXDEG) eidx[node * MAXDEG + pos] = ge; }
    }
  }

  // ---- stage per-edge factors ----
  {
    int e2 = lane >> 1, mg = lane & 1;
    int ge = eb + e2;
    if (ge < E) {
      const float* xp = xsrc + (size_t)ge * 64;
      float4 sq0 = *(const float4*)(xp + mg * 8);
      float4 sq1 = *(const float4*)(xp + mg * 8 + 4);
      float s1a[8] = {sq0.x,sq0.y,sq0.z,sq0.w,sq1.x,sq1.y,sq1.z,sq1.w};
      const float* vp = xp + 16 + mg * 24;
      float la[24];
      #pragma unroll
      for (int qv = 0; qv < 6; ++qv) {
        float4 t = *(const float4*)(vp + qv * 4);
        la[qv*4+0] = t.x; la[qv*4+1] = t.y; la[qv*4+2] = t.z; la[qv*4+3] = t.w;
      }
      float4 shq = *(const float4*)(sh + (size_t)ge * 4);
      float s2 = shq.x, v2x = shq.y, v2y = shq.z, v2z = shq.w;
      #pragma unroll
      for (int mi = 0; mi < 8; ++mi) {
        int m = mg * 8 + mi;
        float v1x = la[mi*3], v1y = la[mi*3+1], v1z = la[mi*3+2];
        fss_s[w][m][e2] = (_Float16)(s1a[mi] * s2);
        fvv_s[w][m][e2] = (_Float16)(v1x*v2x + v1y*v2y + v1z*v2z);
        s1h_s[w][m][e2] = (_Float16)s1a[mi];
        v1h_s[w][m][0][e2] = (_Float16)v1x;
        v1h_s[w][m][1][e2] = (_Float16)v1y;
        v1h_s[w][m][2][e2] = (_Float16)v1z;
      }
      if (mg == 0) vq_s[w][e2] = make_float4(v2x, v2y, v2z, s2);
    } else {
      #pragma unroll
      for (int mi = 0; mi < 8; ++mi) {
        int m = mg * 8 + mi;
        fss_s[w][m][e2] = (_Float16)0.f;
        fvv_s[w][m][e2] = (_Float16)0.f;
        s1h_s[w][m][e2] = (_Float16)0.f;
        v1h_s[w][m][0][e2] = (_Float16)0.f;
        v1h_s[w][m][1][e2] = (_Float16)0.f;
        v1h_s[w][m][2][e2] = (_Float16)0.f;
      }
      if (mg == 0) vq_s[w][e2] = make_float4(0,0,0,0);
    }
  }

  // ---- layer 1 ----
  {
    bf8 ah[2], al[2];
    #pragma unroll
    for (int g = 0; g < 2; ++g) {
      int gea = eb + g * 16 + l16; if (gea > E - 1) gea = E - 1;
      const float* ep = ea + (size_t)gea * 32 + quad * 8;
      float4 p0 = *(const float4*)ep;
      float4 p1 = *(const float4*)(ep + 4);
      float pv[8] = {p0.x,p0.y,p0.z,p0.w,p1.x,p1.y,p1.z,p1.w};
      #pragma unroll
      for (int j = 0; j < 8; ++j) {
        unsigned short hi = f2bf(pv[j]);
        ah[g][j] = (short)hi;
        al[g][j] = (short)f2bf(pv[j] - bf2f(hi));
      }
    }
    const unsigned short* wb1 = we1x + lane * 8;
    #pragma unroll 2
    for (int c = 0; c < 8; ++c) {
      bf8 bh = *(const bf8*)(wb1 + c * 1024);
      bf8 bl = *(const bf8*)(wb1 + c * 1024 + 512);
      float bias = be1[c * 16 + l16];
      #pragma unroll
      for (int g = 0; g < 2; ++g) {
        f32x4 hc = {bias, bias, bias, bias};
        hc = __builtin_amdgcn_mfma_f32_16x16x32_bf16(al[g], bh, hc, 0, 0, 0);
        hc = __builtin_amdgcn_mfma_f32_16x16x32_bf16(ah[g], bl, hc, 0, 0, 0);
        hc = __builtin_amdgcn_mfma_f32_16x16x32_bf16(ah[g], bh, hc, 0, 0, 0);
        #pragma unroll
        for (int r = 0; r < 4; ++r)
          h_s[w][g * 16 + quad * 4 + r][c * 16 + l16] = (_Float16)fmaxf(hc[r], 0.f);
      }
    }
  }

  STAGEB(&Bsm[0][0], 0)
  __syncthreads();

  f16x8 af[2][4];
  #pragma unroll
  for (int g = 0; g < 2; ++g)
    #pragma unroll
    for (int ch = 0; ch < 4; ++ch)
      af[g][ch] = *(const f16x8*)&h_s[w][g * 16 + l16][ch * 32 + quad * 8];

  const float* bp = be2p + l16 * 2;

  float m0a[2][4] = {{0,0,0,0},{0,0,0,0}}, m0b[2][4] = {{0,0,0,0},{0,0,0,0}};
  int p = 0;

  // ---- section 1: ss ----
  #pragma unroll 1
  for (int i = 0; i < 16; ++i) {
    STAGEB(&Bsm[(p + 1) & 1][0], p + 1)
    const _Float16* bL = &Bsm[p & 1][lane * 8];
    LOADB_LDS(bL)
    float2 bias2 = *(const float2*)(bp + p * 32);
    f32x4 wa[2], wb[2];
    chains2(af[0], af[1], b0,b1,b2,b3,b4,b5,b6,b7, bias2, wa, wb);
    #pragma unroll
    for (int g = 0; g < 2; ++g) {
      f16x4 fv = *(const f16x4*)&fss_s[w][i][g * 16 + quad * 4];
      #pragma unroll
      for (int r = 0; r < 4; ++r) {
        float f = (float)fv[r];
        m0a[g][r] = fmaf(wa[g][r], f, m0a[g][r]);
        m0b[g][r] = fmaf(wb[g][r], f, m0b[g][r]);
      }
    }
    __syncthreads();
    ++p;
  }

  // ---- section 2: vv0 ----
  #pragma unroll 1
  for (int i = 0; i < 16; ++i) {
    STAGEB(&Bsm[(p + 1) & 1][0], p + 1)
    const _Float16* bL = &Bsm[p & 1][lane * 8];
    LOADB_LDS(bL)
    float2 bias2 = *(const float2*)(bp + p * 32);
    f32x4 wa[2], wb[2];
    chains2(af[0], af[1], b0,b1,b2,b3,b4,b5,b6,b7, bias2, wa, wb);
    #pragma unroll
    for (int g = 0; g < 2; ++g) {
      f16x4 fv = *(const f16x4*)&fvv_s[w][i][g * 16 + quad * 4];
      #pragma unroll
      for (int r = 0; r < 4; ++r) {
        float f = (float)fv[r];
        m0a[g][r] = fmaf(wa[g][r], f, m0a[g][r]);
        m0b[g][r] = fmaf(wb[g][r], f, m0b[g][r]);
      }
    }
    __syncthreads();
    ++p;
  }

  // ---- emit out0 ----
  #pragma unroll
  for (int g = 0; g < 2; ++g)
    #pragma unroll
    for (int r = 0; r < 4; ++r) {
      int ge = eb + g * 16 + quad * 4 + r;
      if (ge < E) {
        if (MSG) {
          float* mp = outp + (size_t)ge * 80;
          mp[l16]      = m0a[g][r];
          mp[16 + l16] = m0b[g][r];
        } else {
          float* ap = outp + (size_t)dst[ge] * 80;
          atomicAdd(ap + l16,      m0a[g][r]);
          atomicAdd(ap + 16 + l16, m0b[g][r]);
        }
      }
    }

  // ---- section 3: sv ----
  float sg[2][4] = {{0,0,0,0},{0,0,0,0}};
  #pragma unroll 1
  for (int i = 0; i < 8; ++i) {
    STAGEB(&Bsm[(p + 1) & 1][0], p + 1)
    const _Float16* bL = &Bsm[p & 1][lane * 8];
    LOADB_LDS(bL)
    float2 bias2 = *(const float2*)(bp + p * 32);
    f32x4 wa[2], wb[2];
    chains2(af[0], af[1], b0,b1,b2,b3,b4,b5,b6,b7, bias2, wa, wb);
    #pragma unroll
    for (int g = 0; g < 2; ++g) {
      f16x4 sA = *(const f16x4*)&s1h_s[w][2*i][g * 16 + quad * 4];
      f16x4 sB = *(const f16x4*)&s1h_s[w][2*i + 1][g * 16 + quad * 4];
      #pragma unroll
      for (int r = 0; r < 4; ++r)
        sg[g][r] = fmaf(wb[g][r], (float)sB[r], fmaf(wa[g][r], (float)sA[r], sg[g][r]));
    }
    __syncthreads();
    ++p;
  }
  float4 vq[2][4];
  #pragma unroll
  for (int g = 0; g < 2; ++g)
    #pragma unroll
    for (int r = 0; r < 4; ++r) vq[g][r] = vq_s[w][g * 16 + quad * 4 + r];

  float m1x[2][4], m1y[2][4], m1z[2][4];
  #pragma unroll
  for (int g = 0; g < 2; ++g)
    #pragma unroll
    for (int r = 0; r < 4; ++r) {
      m1x[g][r] = sg[g][r] * vq[g][r].x;
      m1y[g][r] = sg[g][r] * vq[g][r].y;
      m1z[g][r] = sg[g][r] * vq[g][r].z;
    }

  // ---- section 4: vs ----
  {
    float ux[2][4] = {{0,0,0,0},{0,0,0,0}}, uy[2][4] = {{0,0,0,0},{0,0,0,0}},
          uz[2][4] = {{0,0,0,0},{0,0,0,0}};
    #pragma unroll 1
    for (int i = 0; i < 8; ++i) {
      STAGEB(&Bsm[(p + 1) & 1][0], p + 1)
      const _Float16* bL = &Bsm[p & 1][lane * 8];
      LOADB_LDS(bL)
      float2 bias2 = *(const float2*)(bp + p * 32);
      f32x4 wa[2], wb[2];
      chains2(af[0], af[1], b0,b1,b2,b3,b4,b5,b6,b7, bias2, wa, wb);
      #pragma unroll
      for (int g = 0; g < 2; ++g) {
        f16x4 xA = *(const f16x4*)&v1h_s[w][2*i][0][g*16 + quad*4];
        f16x4 xB = *(const f16x4*)&v1h_s[w][2*i+1][0][g*16 + quad*4];
        f16x4 yA = *(const f16x4*)&v1h_s[w][2*i][1][g*16 + quad*4];
        f16x4 yB = *(const f16x4*)&v1h_s[w][2*i+1][1][g*16 + quad*4];
        f16x4 zA = *(const f16x4*)&v1h_s[w][2*i][2][g*16 + quad*4];
        f16x4 zB = *(const f16x4*)&v1h_s[w][2*i+1][2][g*16 + quad*4];
        #pragma unroll
        for (int r = 0; r < 4; ++r) {
          ux[g][r] = fmaf(wb[g][r], (float)xB[r], fmaf(wa[g][r], (float)xA[r], ux[g][r]));
          uy[g][r] = fmaf(wb[g][r], (float)yB[r], fmaf(wa[g][r], (float)yA[r], uy[g][r]));
          uz[g][r] = fmaf(wb[g][r], (float)zB[r], fmaf(wa[g][r], (float)zA[r], uz[g][r]));
        }
      }
      __syncthreads();
      ++p;
    }
    #pragma unroll
    for (int g = 0; g < 2; ++g)
      #pragma unroll
      for (int r = 0; r < 4; ++r) {
        m1x[g][r] = fmaf(vq[g][r].w, ux[g][r], m1x[g][r]);
        m1y[g][r] = fmaf(vq[g][r].w, uy[g][r], m1y[g][r]);
        m1z[g][r] = fmaf(vq[g][r].w, uz[g][r], m1z[g][r]);
      }
  }

  // ---- section 5: vv1 ----
  {
    float ux[2][4] = {{0,0,0,0},{0,0,0,0}}, uy[2][4] = {{0,0,0,0},{0,0,0,0}},
          uz[2][4] = {{0,0,0,0},{0,0,0,0}};
    #pragma unroll 1
    for (int i = 0; i < 8; ++i) {
      if (p + 1 < 56) STAGEB(&Bsm[(p + 1) & 1][0], p + 1)
      const _Float16* bL = &Bsm[p & 1][lane * 8];
      LOADB_LDS(bL)
      float2 bias2 = *(const float2*)(bp + p * 32);
      f32x4 wa[2], wb[2];
      chains2(af[0], af[1], b0,b1,b2,b3,b4,b5,b6,b7, bias2, wa, wb);
      #pragma unroll
      for (int g = 0; g < 2; ++g) {
        f16x4 xA = *(const f16x4*)&v1h_s[w][2*i][0][g*16 + quad*4];
        f16x4 xB = *(const f16x4*)&v1h_s[w][2*i+1][0][g*16 + quad*4];
        f16x4 yA = *(const f16x4*)&v1h_s[w][2*i][1][g*16 + quad*4];
        f16x4 yB = *(const f16x4*)&v1h_s[w][2*i+1][1][g*16 + quad*4];
        f16x4 zA = *(const f16x4*)&v1h_s[w][2*i][2][g*16 + quad*4];
        f16x4 zB = *(const f16x4*)&v1h_s[w][2*i+1][2][g*16 + quad*4];
        #pragma unroll
        for (int r = 0; r < 4; ++r) {
          ux[g][r] = fmaf(wb[g][r], (float)xB[r], fmaf(wa[g][r], (float)xA[r], ux[g][r]));
          uy[g][r] = fmaf(wb[g][r], (float)yB[r], fmaf(wa[g][r], (float)yA[r], uy[g][r]));
          uz[g][r] = fmaf(wb[g][r], (float)zB[r], fmaf(wa[g][r], (float)zA[r], uz[g][r]));
        }
      }
      __syncthreads();
      ++p;
    }
    #pragma unroll
    for (int g = 0; g < 2; ++g)
      #pragma unroll
      for (int r = 0; r < 4; ++r) {
        m1x[g][r] = fmaf(uy[g][r], vq[g][r].z, m1x[g][r]);
        m1x[g][r] = fmaf(-uz[g][r], vq[g][r].y, m1x[g][r]);
        m1y[g][r] = fmaf(uz[g][r], vq[g][r].x, m1y[g][r]);
        m1y[g][r] = fmaf(-ux[g][r], vq[g][r].z, m1y[g][r]);
        m1z[g][r] = fmaf(ux[g][r], vq[g][r].y, m1z[g][r]);
        m1z[g][r] = fmaf(-uy[g][r], vq[g][r].x, m1z[g][r]);
      }
  }

  // ---- emit out1 ----
  #pragma unroll
  for (int g = 0; g < 2; ++g)
    #pragma unroll
    for (int r = 0; r < 4; ++r) {
      int ge = eb + g * 16 + quad * 4 + r;
      if (ge < E) {
        if (MSG) {
          float* mp = outp + (size_t)ge * 80;
          mp[32 + l16*3 + 0] = m1x[g][r];
          mp[32 + l16*3 + 1] = m1y[g][r];
          mp[32 + l16*3 + 2] = m1z[g][r];
        } else {
          float* ap = outp + (size_t)dst[ge] * 80;
          atomicAdd(ap + 32 + l16*3 + 0, m1x[g][r]);
          atomicAdd(ap + 32 + l16*3 + 1, m1y[g][r]);
          atomicAdd(ap + 32 + l16*3 + 2, m1z[g][r]);
        }
      }
    }
  #undef STAGEB
}

// ---- node gather (MSG path): one node per 128-thread block ----
__global__ __launch_bounds__(128) void node_gather_kernel(
    const float* __restrict__ msg, const int* __restrict__ eidx,
    const int* __restrict__ cntp,
    const float* __restrict__ xdst, const float* __restrict__ Wr0,
    const float* __restrict__ Wr1, float* __restrict__ out, int N)
{
  int n = blockIdx.x;
  if (n >= N) return;
  int j = threadIdx.x;
  int c0 = cntp[n];
  int deg = c0 < MAXDEG ? c0 : MAXDEG;
  float inv = 1.0f / fmaxf((float)c0, 1.0f);
  __shared__ float s_sum[80];
  if (j < 80) {
    float s = 0.f;
    const int* ep = eidx + (size_t)n * MAXDEG;
    int i = 0;
    for (; i + 1 < deg; i += 2) {
      int e0 = ep[i], e1 = ep[i + 1];
      s += msg[(size_t)e0 * 80 + j] + msg[(size_t)e1 * 80 + j];
    }
    if (i < deg) s += msg[(size_t)ep[i] * 80 + j];
    s_sum[j] = s * inv;
  }
  __syncthreads();
  if (j >= 64) return;
  const float* xd = xdst + (size_t)n * 64;
  float* op = out + (size_t)n * 64;
  if (j < 16) {
    float s = 0.f;
    #pragma unroll
    for (int m = 0; m < 16; ++m) s = fmaf(xd[m], Wr0[m * 32 + j], s);
    op[j] = fmaxf(s_sum[j] + 0.25f * s, 0.f);
  } else {
    int jj = j - 16;
    int o = (jj * 86) >> 8;
    int c = jj - o * 3;
    float tg = 0.f, v = 0.f;
    #pragma unroll
    for (int m = 0; m < 16; ++m) {
      tg = fmaf(xd[m], Wr0[m * 32 + 16 + o], tg);
      v  = fmaf(xd[16 + m * 3 + c], Wr1[m * 16 + o], v);
    }
    float g = 1.0f / (1.0f + expf(-(s_sum[16 + o] + 0.25f * tg)));
    op[16 + jj] = (s_sum[32 + jj] + 0.25f * v) * g;
  }
}

// ---- node epilogue (atomic fallback path) ----
__global__ __launch_bounds__(256) void node_kernel(
    const float* __restrict__ accn, const int* __restrict__ cntp,
    const float* __restrict__ xdst, const float* __restrict__ Wr0,
    const float* __restrict__ Wr1, float* __restrict__ out, int N)
{
  int idx = blockIdx.x * 256 + threadIdx.x;
  int n = idx >> 6, j = idx & 63;
  if (n >= N) return;
  float inv = 1.0f / fmaxf((float)cntp[n], 1.0f);
  const float* ap = accn + (size_t)n * 80;
  const float* xd = xdst + (size_t)n * 64;
  float* op = out + (size_t)n * 64;
  if (j < 16) {
    float s = 0.f;
    #pragma unroll
    for (int m = 0; m < 16; ++m) s = fmaf(xd[m], Wr0[m * 32 + j], s);
    op[j] = fmaxf(ap[j] * inv + 0.25f * s, 0.f);
  } else {
    int jj = j - 16;
    int o = (jj * 86) >> 8;
    int c = jj - o * 3;
    float tg = 0.f, v = 0.f;
    #pragma unroll
    for (int m = 0; m < 16; ++m) {
      tg = fmaf(xd[m], Wr0[m * 32 + 16 + o], tg);
      v  = fmaf(xd[16 + m * 3 + c], Wr1[m * 16 + o], v);
    }
    float g = 1.0f / (1.0f + expf(-(ap[16 + o] * inv + 0.25f * tg)));
    op[16 + jj] = (ap[32 + jj] * inv + 0.25f * v) * g;
  }
}

extern "C" void kernel_launch(void* const* d_in, const int* in_sizes, int n_in,
                              void* d_out, int out_size, void* d_ws, size_t ws_size,
                              hipStream_t stream)
{
  const int*   dst  = (const int*)d_in[0];
  const float* xsrc = (const float*)d_in[1];
  const float* xdst = (const float*)d_in[2];
  const float* sh   = (const float*)d_in[3];
  const float* ea   = (const float*)d_in[4];
  const float* We1  = (const float*)d_in[5];
  const float* be1  = (const float*)d_in[6];
  const float* We2  = (const float*)d_in[7];
  const float* be2  = (const float*)d_in[8];
  const float* Wr0  = (const float*)d_in[9];
  const float* Wr1  = (const float*)d_in[10];
  const int E = in_sizes[0];
  const int N = in_sizes[2] / 64;

  char* ws = (char*)d_ws;
  _Float16* we2h = (_Float16*)ws;                           // 458,752 B
  unsigned short* we1x = (unsigned short*)(ws + 458752);    //  16,384 B
  float* be2p = (float*)(ws + 475136);                      //   7,424 B
  int*   cntp = (int*)(ws + 482560);                        // N*4
  size_t off = 482560 + (size_t)N * 4;
  off = (off + 15) & ~(size_t)15;

  size_t need_msg = off + (size_t)N * MAXDEG * 4 + (size_t)E * 80 * 4;
  bool use_msg = (ws_size >= need_msg);

  prep_kernel<<<(30976 + N + 255) / 256, 256, 0, stream>>>(We1, We2, be2,
      we1x, we2h, be2p, cntp, N);

  if (use_msg) {
    int* eidx = (int*)(ws + off);
    float* msg = (float*)(ws + off + (size_t)N * MAXDEG * 4);
    edge_kernel<true><<<(E + 127) / 128, 256, 0, stream>>>(ea, xsrc, sh, dst, be1,
        we1x, we2h, be2p, msg, eidx, cntp, E);
    node_gather_kernel<<<N, 128, 0, stream>>>(msg, eidx, cntp, xdst, Wr0, Wr1,
        (float*)d_out, N);
  } else {
    float* accn = (float*)(ws + off);                       // N*320
    hipMemsetAsync(accn, 0, (size_t)N * 320, stream);
    edge_kernel<false><<<(E + 127) / 128, 256, 0, stream>>>(ea, xsrc, sh, dst, be1,
        we1x, we2h, be2p, accn, (int*)nullptr, cntp, E);
    node_kernel<<<((size_t)N * 64 + 255) / 256, 256, 0, stream>>>(accn, cntp,
        xdst, Wr0, Wr1, (float*)d_out, N);
  }
}

// Round 12
// 199.451 us; speedup vs baseline: 1.3629x; 1.0238x over previous
//
#include <hip/hip_runtime.h>
#include <math.h>

#define WNUM 1792
#define HID 128

#define INV3C 0.5773502691896258f
#define INV2C 0.7071067811865476f
#define A0C   0.17677669529663687f   /* 1/sqrt(32) */
#define A1C   0.14433756729740643f   /* 1/sqrt(48) */
#define MAXDEG 64

typedef short bf8 __attribute__((ext_vector_type(8)));
typedef _Float16 f16x8 __attribute__((ext_vector_type(8)));
typedef _Float16 f16x4 __attribute__((ext_vector_type(4)));
typedef float f32x4 __attribute__((ext_vector_type(4)));

__device__ inline unsigned short f2bf(float f) {
  union { float f; unsigned u; } v; v.f = f;
  unsigned r = v.u + 0x7FFFu + ((v.u >> 16) & 1u);   // RNE
  return (unsigned short)(r >> 16);
}
__device__ inline float bf2f(unsigned short h) {
  union { unsigned u; float f; } v; v.u = ((unsigned)h) << 16;
  return v.f;
}
__device__ inline float wscale(int t) {
  if (t < 32) return A0C;
  if (t < 64) return A0C * INV3C;
  if (t < 96) return A1C;
  return A1C * INV2C;
}

// ---- prep: weight staging + cnt zeroing (layouts unchanged) ----
__global__ __launch_bounds__(256) void prep_kernel(
    const float* __restrict__ We1, const float* __restrict__ We2,
    const float* __restrict__ be2,
    unsigned short* __restrict__ we1x, _Float16* __restrict__ we2h,
    float* __restrict__ be2p, int* __restrict__ cntp, int N)
{
  int i = blockIdx.x * 256 + threadIdx.x;
  if (i < 28672) {
    int t = i >> 8, c = (i >> 6) & 3, lane = i & 63;
    int quad = lane >> 4, l15 = lane & 15;
    int col = t * 16 + l15;
    float sc = wscale(t);
    f16x8 v;
    #pragma unroll
    for (int j = 0; j < 8; ++j) {
      int k = c * 32 + quad * 8 + j;
      v[j] = (_Float16)(We2[(size_t)k * WNUM + col] * sc);
    }
    *(f16x8*)(we2h + (size_t)t * 2048 + c * 512 + lane * 8) = v;
  } else if (i < 29184) {
    int q = i - 28672;
    int c1 = q >> 6, lane = q & 63;
    int quad = lane >> 4, l15 = lane & 15;
    int col = c1 * 16 + l15;
    bf8 hh, ll;
    #pragma unroll
    for (int j = 0; j < 8; ++j) {
      int k = quad * 8 + j;
      float v = We1[k * HID + col];
      unsigned short hi = f2bf(v);
      hh[j] = (short)hi;
      ll[j] = (short)f2bf(v - bf2f(hi));
    }
    *(bf8*)(we1x + c1 * 1024 + lane * 8) = hh;
    *(bf8*)(we1x + c1 * 1024 + 512 + lane * 8) = ll;
  } else if (i < 30976) {
    int q = i - 29184;
    int t = q >> 4, l16 = q & 15;
    be2p[(t >> 1) * 32 + l16 * 2 + (t & 1)] = be2[q] * wscale(t);
  } else if (i < 30976 + N) {
    cntp[i - 30976] = 0;
  }
}

__device__ inline void chains2(const f16x8* a0, const f16x8* a1,
    f16x8 b0, f16x8 b1, f16x8 b2, f16x8 b3,
    f16x8 b4, f16x8 b5, f16x8 b6, f16x8 b7,
    float2 bias, f32x4* wa, f32x4* wb)
{
  f32x4 ca0 = {bias.x, bias.x, bias.x, bias.x};
  f32x4 cb0 = {bias.y, bias.y, bias.y, bias.y};
  f32x4 ca1 = ca0, cb1 = cb0;
  ca0 = __builtin_amdgcn_mfma_f32_16x16x32_f16(a0[0], b0, ca0, 0, 0, 0);
  cb0 = __builtin_amdgcn_mfma_f32_16x16x32_f16(a0[0], b4, cb0, 0, 0, 0);
  ca1 = __builtin_amdgcn_mfma_f32_16x16x32_f16(a1[0], b0, ca1, 0, 0, 0);
  cb1 = __builtin_amdgcn_mfma_f32_16x16x32_f16(a1[0], b4, cb1, 0, 0, 0);
  ca0 = __builtin_amdgcn_mfma_f32_16x16x32_f16(a0[1], b1, ca0, 0, 0, 0);
  cb0 = __builtin_amdgcn_mfma_f32_16x16x32_f16(a0[1], b5, cb0, 0, 0, 0);
  ca1 = __builtin_amdgcn_mfma_f32_16x16x32_f16(a1[1], b1, ca1, 0, 0, 0);
  cb1 = __builtin_amdgcn_mfma_f32_16x16x32_f16(a1[1], b5, cb1, 0, 0, 0);
  ca0 = __builtin_amdgcn_mfma_f32_16x16x32_f16(a0[2], b2, ca0, 0, 0, 0);
  cb0 = __builtin_amdgcn_mfma_f32_16x16x32_f16(a0[2], b6, cb0, 0, 0, 0);
  ca1 = __builtin_amdgcn_mfma_f32_16x16x32_f16(a1[2], b2, ca1, 0, 0, 0);
  cb1 = __builtin_amdgcn_mfma_f32_16x16x32_f16(a1[2], b6, cb1, 0, 0, 0);
  ca0 = __builtin_amdgcn_mfma_f32_16x16x32_f16(a0[3], b3, ca0, 0, 0, 0);
  cb0 = __builtin_amdgcn_mfma_f32_16x16x32_f16(a0[3], b7, cb0, 0, 0, 0);
  ca1 = __builtin_amdgcn_mfma_f32_16x16x32_f16(a1[3], b3, ca1, 0, 0, 0);
  cb1 = __builtin_amdgcn_mfma_f32_16x16x32_f16(a1[3], b7, cb1, 0, 0, 0);
  wa[0] = ca0; wb[0] = cb0; wa[1] = ca1; wb[1] = cb1;
}

__device__ inline void pair_mm(const _Float16* bL, const float* bp, int p,
                               const f16x8 (&af)[2][4], f32x4* wa, f32x4* wb)
{
  f16x8 b0 = *(const f16x8*)(bL);
  f16x8 b1 = *(const f16x8*)(bL + 512);
  f16x8 b2 = *(const f16x8*)(bL + 1024);
  f16x8 b3 = *(const f16x8*)(bL + 1536);
  f16x8 b4 = *(const f16x8*)(bL + 2048);
  f16x8 b5 = *(const f16x8*)(bL + 2560);
  f16x8 b6 = *(const f16x8*)(bL + 3072);
  f16x8 b7 = *(const f16x8*)(bL + 3584);
  float2 bias2 = *(const float2*)(bp + p * 32);
  chains2(af[0], af[1], b0, b1, b2, b3, b4, b5, b6, b7, bias2, wa, wb);
}

// ---- fused edge kernel: 4 waves x 32 edges; quad-buffered LDS B, 2-pair epochs ----
template <bool MSG>
__global__ __launch_bounds__(256, 2) void edge_kernel(
    const float* __restrict__ ea, const float* __restrict__ xsrc,
    const float* __restrict__ sh, const int* __restrict__ dst,
    const float* __restrict__ be1,
    const unsigned short* __restrict__ we1x, const _Float16* __restrict__ we2h,
    const float* __restrict__ be2p,
    float* __restrict__ outp, int* __restrict__ eidx, int* __restrict__ cntp, int E)
{
  const int lane = threadIdx.x & 63;
  const int w    = threadIdx.x >> 6;
  const int quad = lane >> 4;
  const int l16  = lane & 15;
  const int eb   = (blockIdx.x * 4 + w) * 32;

  // h staging (pre-loop) overlays the B quad-buffer (K-loop) — 34.8 KB region
  __shared__ union SMem {
    _Float16 h[4][32][136];
    _Float16 B[4][4096];
  } uS;
  __shared__ _Float16 fss_s[4][16][32];
  __shared__ _Float16 fvv_s[4][16][32];
  __shared__ _Float16 s1h_s[4][16][32];
  __shared__ _Float16 v1h_s[4][16][3][32];
  __shared__ float4 vq_s[4][32];

  #define STAGE_PAIR(p) { \
    const _Float16* gsrc_ = we2h + (size_t)(p) * 4096; \
    _Float16* ldst_ = &uS.B[(p) & 3][0]; \
    __builtin_amdgcn_global_load_lds( \
      (const __attribute__((address_space(1))) void*)(gsrc_ + (w * 2) * 512 + lane * 8), \
      (__attribute__((address_space(3))) void*)(ldst_ + (w * 2) * 512), 16, 0, 0); \
    __builtin_amdgcn_global_load_lds( \
      (const __attribute__((address_space(1))) void*)(gsrc_ + (w * 2 + 1) * 512 + lane * 8), \
      (__attribute__((address_space(3))) void*)(ldst_ + (w * 2 + 1) * 512), 16, 0, 0); \
  }

  // slot-fill / count early
  if (lane < 32) {
    int ge = eb + lane;
    if (ge < E) {
      int node = dst[ge];
      int pos = atomicAdd(cntp + node, 1);
      if (MSG) { if (pos < MAXDEG) eidx[node * MAXDEG + pos] = ge; }
    }
  }

  // ---- stage per-edge factors ----
  {
    int e2 = lane >> 1, mg = lane & 1;
    int ge = eb + e2;
    if (ge < E) {
      const float* xp = xsrc + (size_t)ge * 64;
      float4 sq0 = *(const float4*)(xp + mg * 8);
      float4 sq1 = *(const float4*)(xp + mg * 8 + 4);
      float s1a[8] = {sq0.x,sq0.y,sq0.z,sq0.w,sq1.x,sq1.y,sq1.z,sq1.w};
      const float* vp = xp + 16 + mg * 24;
      float la[24];
      #pragma unroll
      for (int qv = 0; qv < 6; ++qv) {
        float4 t = *(const float4*)(vp + qv * 4);
        la[qv*4+0] = t.x; la[qv*4+1] = t.y; la[qv*4+2] = t.z; la[qv*4+3] = t.w;
      }
      float4 shq = *(const float4*)(sh + (size_t)ge * 4);
      float s2 = shq.x, v2x = shq.y, v2y = shq.z, v2z = shq.w;
      #pragma unroll
      for (int mi = 0; mi < 8; ++mi) {
        int m = mg * 8 + mi;
        float v1x = la[mi*3], v1y = la[mi*3+1], v1z = la[mi*3+2];
        fss_s[w][m][e2] = (_Float16)(s1a[mi] * s2);
        fvv_s[w][m][e2] = (_Float16)(v1x*v2x + v1y*v2y + v1z*v2z);
        s1h_s[w][m][e2] = (_Float16)s1a[mi];
        v1h_s[w][m][0][e2] = (_Float16)v1x;
        v1h_s[w][m][1][e2] = (_Float16)v1y;
        v1h_s[w][m][2][e2] = (_Float16)v1z;
      }
      if (mg == 0) vq_s[w][e2] = make_float4(v2x, v2y, v2z, s2);
    } else {
      #pragma unroll
      for (int mi = 0; mi < 8; ++mi) {
        int m = mg * 8 + mi;
        fss_s[w][m][e2] = (_Float16)0.f;
        fvv_s[w][m][e2] = (_Float16)0.f;
        s1h_s[w][m][e2] = (_Float16)0.f;
        v1h_s[w][m][0][e2] = (_Float16)0.f;
        v1h_s[w][m][1][e2] = (_Float16)0.f;
        v1h_s[w][m][2][e2] = (_Float16)0.f;
      }
      if (mg == 0) vq_s[w][e2] = make_float4(0,0,0,0);
    }
  }

  // ---- layer 1 ----
  {
    bf8 ah[2], al[2];
    #pragma unroll
    for (int g = 0; g < 2; ++g) {
      int gea = eb + g * 16 + l16; if (gea > E - 1) gea = E - 1;
      const float* ep = ea + (size_t)gea * 32 + quad * 8;
      float4 p0 = *(const float4*)ep;
      float4 p1 = *(const float4*)(ep + 4);
      float pv[8] = {p0.x,p0.y,p0.z,p0.w,p1.x,p1.y,p1.z,p1.w};
      #pragma unroll
      for (int j = 0; j < 8; ++j) {
        unsigned short hi = f2bf(pv[j]);
        ah[g][j] = (short)hi;
        al[g][j] = (short)f2bf(pv[j] - bf2f(hi));
      }
    }
    const unsigned short* wb1 = we1x + lane * 8;
    #pragma unroll 2
    for (int c = 0; c < 8; ++c) {
      bf8 bh = *(const bf8*)(wb1 + c * 1024);
      bf8 bl = *(const bf8*)(wb1 + c * 1024 + 512);
      float bias = be1[c * 16 + l16];
      #pragma unroll
      for (int g = 0; g < 2; ++g) {
        f32x4 hc = {bias, bias, bias, bias};
        hc = __builtin_amdgcn_mfma_f32_16x16x32_bf16(al[g], bh, hc, 0, 0, 0);
        hc = __builtin_amdgcn_mfma_f32_16x16x32_bf16(ah[g], bl, hc, 0, 0, 0);
        hc = __builtin_amdgcn_mfma_f32_16x16x32_bf16(ah[g], bh, hc, 0, 0, 0);
        #pragma unroll
        for (int r = 0; r < 4; ++r)
          uS.h[w][g * 16 + quad * 4 + r][c * 16 + l16] = (_Float16)fmaxf(hc[r], 0.f);
      }
    }
  }
  __syncthreads();

  // ---- A fragments (must finish before B-staging overwrites the overlay) ----
  f16x8 af[2][4];
  #pragma unroll
  for (int g = 0; g < 2; ++g)
    #pragma unroll
    for (int ch = 0; ch < 4; ++ch)
      af[g][ch] = *(const f16x8*)&uS.h[w][g * 16 + l16][ch * 32 + quad * 8];
  __syncthreads();

  // prologue: stage pairs 0,1; drain
  STAGE_PAIR(0)
  STAGE_PAIR(1)
  __syncthreads();

  const float* bp = be2p + l16 * 2;
  float m0a[2][4] = {{0,0,0,0},{0,0,0,0}}, m0b[2][4] = {{0,0,0,0},{0,0,0,0}};

  // ---- section 1: ss (pairs 0..15) ----
  #pragma unroll 1
  for (int i = 0; i < 16; i += 2) {
    STAGE_PAIR(i + 2)
    STAGE_PAIR(i + 3)
    f32x4 wa[2], wb[2];
    pair_mm(&uS.B[i & 3][lane * 8], bp, i, af, wa, wb);
    #pragma unroll
    for (int g = 0; g < 2; ++g) {
      f16x4 fv = *(const f16x4*)&fss_s[w][i][g * 16 + quad * 4];
      #pragma unroll
      for (int r = 0; r < 4; ++r) {
        float f = (float)fv[r];
        m0a[g][r] = fmaf(wa[g][r], f, m0a[g][r]);
        m0b[g][r] = fmaf(wb[g][r], f, m0b[g][r]);
      }
    }
    pair_mm(&uS.B[(i + 1) & 3][lane * 8], bp, i + 1, af, wa, wb);
    #pragma unroll
    for (int g = 0; g < 2; ++g) {
      f16x4 fv = *(const f16x4*)&fss_s[w][i + 1][g * 16 + quad * 4];
      #pragma unroll
      for (int r = 0; r < 4; ++r) {
        float f = (float)fv[r];
        m0a[g][r] = fmaf(wa[g][r], f, m0a[g][r]);
        m0b[g][r] = fmaf(wb[g][r], f, m0b[g][r]);
      }
    }
    __syncthreads();
  }

  // ---- section 2: vv0 (pairs 16..31) ----
  #pragma unroll 1
  for (int i = 0; i < 16; i += 2) {
    int pg = 16 + i;
    STAGE_PAIR(pg + 2)
    STAGE_PAIR(pg + 3)
    f32x4 wa[2], wb[2];
    pair_mm(&uS.B[pg & 3][lane * 8], bp, pg, af, wa, wb);
    #pragma unroll
    for (int g = 0; g < 2; ++g) {
      f16x4 fv = *(const f16x4*)&fvv_s[w][i][g * 16 + quad * 4];
      #pragma unroll
      for (int r = 0; r < 4; ++r) {
        float f = (float)fv[r];
        m0a[g][r] = fmaf(wa[g][r], f, m0a[g][r]);
        m0b[g][r] = fmaf(wb[g][r], f, m0b[g][r]);
      }
    }
    pair_mm(&uS.B[(pg + 1) & 3][lane * 8], bp, pg + 1, af, wa, wb);
    #pragma unroll
    for (int g = 0; g < 2; ++g) {
      f16x4 fv = *(const f16x4*)&fvv_s[w][i + 1][g * 16 + quad * 4];
      #pragma unroll
      for (int r = 0; r < 4; ++r) {
        float f = (float)fv[r];
        m0a[g][r] = fmaf(wa[g][r], f, m0a[g][r]);
        m0b[g][r] = fmaf(wb[g][r], f, m0b[g][r]);
      }
    }
    __syncthreads();
  }

  // ---- emit out0 ----
  #pragma unroll
  for (int g = 0; g < 2; ++g)
    #pragma unroll
    for (int r = 0; r < 4; ++r) {
      int ge = eb + g * 16 + quad * 4 + r;
      if (ge < E) {
        if (MSG) {
          float* mp = outp + (size_t)ge * 80;
          mp[l16]      = m0a[g][r];
          mp[16 + l16] = m0b[g][r];
        } else {
          float* ap = outp + (size_t)dst[ge] * 80;
          atomicAdd(ap + l16,      m0a[g][r]);
          atomicAdd(ap + 16 + l16, m0b[g][r]);
        }
      }
    }

  // ---- section 3: sv (pairs 32..39) ----
  float sg[2][4] = {{0,0,0,0},{0,0,0,0}};
  #pragma unroll 1
  for (int i = 0; i < 8; i += 2) {
    int pg = 32 + i;
    STAGE_PAIR(pg + 2)
    STAGE_PAIR(pg + 3)
    f32x4 wa[2], wb[2];
    pair_mm(&uS.B[pg & 3][lane * 8], bp, pg, af, wa, wb);
    #pragma unroll
    for (int g = 0; g < 2; ++g) {
      f16x4 sA = *(const f16x4*)&s1h_s[w][2*i][g * 16 + quad * 4];
      f16x4 sB = *(const f16x4*)&s1h_s[w][2*i + 1][g * 16 + quad * 4];
      #pragma unroll
      for (int r = 0; r < 4; ++r)
        sg[g][r] = fmaf(wb[g][r], (float)sB[r], fmaf(wa[g][r], (float)sA[r], sg[g][r]));
    }
    pair_mm(&uS.B[(pg + 1) & 3][lane * 8], bp, pg + 1, af, wa, wb);
    #pragma unroll
    for (int g = 0; g < 2; ++g) {
      f16x4 sA = *(const f16x4*)&s1h_s[w][2*i + 2][g * 16 + quad * 4];
      f16x4 sB = *(const f16x4*)&s1h_s[w][2*i + 3][g * 16 + quad * 4];
      #pragma unroll
      for (int r = 0; r < 4; ++r)
        sg[g][r] = fmaf(wb[g][r], (float)sB[r], fmaf(wa[g][r], (float)sA[r], sg[g][r]));
    }
    __syncthreads();
  }
  float4 vq[2][4];
  #pragma unroll
  for (int g = 0; g < 2; ++g)
    #pragma unroll
    for (int r = 0; r < 4; ++r) vq[g][r] = vq_s[w][g * 16 + quad * 4 + r];

  float m1x[2][4], m1y[2][4], m1z[2][4];
  #pragma unroll
  for (int g = 0; g < 2; ++g)
    #pragma unroll
    for (int r = 0; r < 4; ++r) {
      m1x[g][r] = sg[g][r] * vq[g][r].x;
      m1y[g][r] = sg[g][r] * vq[g][r].y;
      m1z[g][r] = sg[g][r] * vq[g][r].z;
    }

  // ---- sections 4+5: vs (40..47) then vv1 (48..55) ----
  #pragma unroll
  for (int sec = 0; sec < 2; ++sec) {
    float ux[2][4] = {{0,0,0,0},{0,0,0,0}}, uy[2][4] = {{0,0,0,0},{0,0,0,0}},
          uz[2][4] = {{0,0,0,0},{0,0,0,0}};
    int base = 40 + sec * 8;
    #pragma unroll 1
    for (int i = 0; i < 8; i += 2) {
      int pg = base + i;
      if (pg + 2 < 56) STAGE_PAIR(pg + 2)
      if (pg + 3 < 56) STAGE_PAIR(pg + 3)
      f32x4 wa[2], wb[2];
      pair_mm(&uS.B[pg & 3][lane * 8], bp, pg, af, wa, wb);
      #pragma unroll
      for (int g = 0; g < 2; ++g) {
        f16x4 xA = *(const f16x4*)&v1h_s[w][2*i][0][g*16 + quad*4];
        f16x4 xB = *(const f16x4*)&v1h_s[w][2*i+1][0][g*16 + quad*4];
        f16x4 yA = *(const f16x4*)&v1h_s[w][2*i][1][g*16 + quad*4];
        f16x4 yB = *(const f16x4*)&v1h_s[w][2*i+1][1][g*16 + quad*4];
        f16x4 zA = *(const f16x4*)&v1h_s[w][2*i][2][g*16 + quad*4];
        f16x4 zB = *(const f16x4*)&v1h_s[w][2*i+1][2][g*16 + quad*4];
        #pragma unroll
        for (int r = 0; r < 4; ++r) {
          ux[g][r] = fmaf(wb[g][r], (float)xB[r], fmaf(wa[g][r], (float)xA[r], ux[g][r]));
          uy[g][r] = fmaf(wb[g][r], (float)yB[r], fmaf(wa[g][r], (float)yA[r], uy[g][r]));
          uz[g][r] = fmaf(wb[g][r], (float)zB[r], fmaf(wa[g][r], (float)zA[r], uz[g][r]));
        }
      }
      pair_mm(&uS.B[(pg + 1) & 3][lane * 8], bp, pg + 1, af, wa, wb);
      #pragma unroll
      for (int g = 0; g < 2; ++g) {
        f16x4 xA = *(const f16x4*)&v1h_s[w][2*i+2][0][g*16 + quad*4];
        f16x4 xB = *(const f16x4*)&v1h_s[w][2*i+3][0][g*16 + quad*4];
        f16x4 yA = *(const f16x4*)&v1h_s[w][2*i+2][1][g*16 + quad*4];
        f16x4 yB = *(const f16x4*)&v1h_s[w][2*i+3][1][g*16 + quad*4];
        f16x4 zA = *(const f16x4*)&v1h_s[w][2*i+2][2][g*16 + quad*4];
        f16x4 zB = *(const f16x4*)&v1h_s[w][2*i+3][2][g*16 + quad*4];
        #pragma unroll
        for (int r = 0; r < 4; ++r) {
          ux[g][r] = fmaf(wb[g][r], (float)xB[r], fmaf(wa[g][r], (float)xA[r], ux[g][r]));
          uy[g][r] = fmaf(wb[g][r], (float)yB[r], fmaf(wa[g][r], (float)yA[r], uy[g][r]));
          uz[g][r] = fmaf(wb[g][r], (float)zB[r], fmaf(wa[g][r], (float)zA[r], uz[g][r]));
        }
      }
      __syncthreads();
    }
    if (sec == 0) {
      #pragma unroll
      for (int g = 0; g < 2; ++g)
        #pragma unroll
        for (int r = 0; r < 4; ++r) {
          m1x[g][r] = fmaf(vq[g][r].w, ux[g][r], m1x[g][r]);
          m1y[g][r] = fmaf(vq[g][r].w, uy[g][r], m1y[g][r]);
          m1z[g][r] = fmaf(vq[g][r].w, uz[g][r], m1z[g][r]);
        }
    } else {
      #pragma unroll
      for (int g = 0; g < 2; ++g)
        #pragma unroll
        for (int r = 0; r < 4; ++r) {
          m1x[g][r] = fmaf(uy[g][r], vq[g][r].z, m1x[g][r]);
          m1x[g][r] = fmaf(-uz[g][r], vq[g][r].y, m1x[g][r]);
          m1y[g][r] = fmaf(uz[g][r], vq[g][r].x, m1y[g][r]);
          m1y[g][r] = fmaf(-ux[g][r], vq[g][r].z, m1y[g][r]);
          m1z[g][r] = fmaf(ux[g][r], vq[g][r].y, m1z[g][r]);
          m1z[g][r] = fmaf(-uy[g][r], vq[g][r].x, m1z[g][r]);
        }
    }
  }

  // ---- emit out1 ----
  #pragma unroll
  for (int g = 0; g < 2; ++g)
    #pragma unroll
    for (int r = 0; r < 4; ++r) {
      int ge = eb + g * 16 + quad * 4 + r;
      if (ge < E) {
        if (MSG) {
          float* mp = outp + (size_t)ge * 80;
          mp[32 + l16*3 + 0] = m1x[g][r];
          mp[32 + l16*3 + 1] = m1y[g][r];
          mp[32 + l16*3 + 2] = m1z[g][r];
        } else {
          float* ap = outp + (size_t)dst[ge] * 80;
          atomicAdd(ap + 32 + l16*3 + 0, m1x[g][r]);
          atomicAdd(ap + 32 + l16*3 + 1, m1y[g][r]);
          atomicAdd(ap + 32 + l16*3 + 2, m1z[g][r]);
        }
      }
    }
  #undef STAGE_PAIR
}

// ---- node gather (MSG path) ----
__global__ __launch_bounds__(128) void node_gather_kernel(
    const float* __restrict__ msg, const int* __restrict__ eidx,
    const int* __restrict__ cntp,
    const float* __restrict__ xdst, const float* __restrict__ Wr0,
    const float* __restrict__ Wr1, float* __restrict__ out, int N)
{
  int n = blockIdx.x;
  if (n >= N) return;
  int j = threadIdx.x;
  int c0 = cntp[n];
  int deg = c0 < MAXDEG ? c0 : MAXDEG;
  float inv = 1.0f / fmaxf((float)c0, 1.0f);
  __shared__ float s_sum[80];
  if (j < 80) {
    float s = 0.f;
    const int* ep = eidx + (size_t)n * MAXDEG;
    int i = 0;
    for (; i + 1 < deg; i += 2) {
      int e0 = ep[i], e1 = ep[i + 1];
      s += msg[(size_t)e0 * 80 + j] + msg[(size_t)e1 * 80 + j];
    }
    if (i < deg) s += msg[(size_t)ep[i] * 80 + j];
    s_sum[j] = s * inv;
  }
  __syncthreads();
  if (j >= 64) return;
  const float* xd = xdst + (size_t)n * 64;
  float* op = out + (size_t)n * 64;
  if (j < 16) {
    float s = 0.f;
    #pragma unroll
    for (int m = 0; m < 16; ++m) s = fmaf(xd[m], Wr0[m * 32 + j], s);
    op[j] = fmaxf(s_sum[j] + 0.25f * s, 0.f);
  } else {
    int jj = j - 16;
    int o = (jj * 86) >> 8;
    int c = jj - o * 3;
    float tg = 0.f, v = 0.f;
    #pragma unroll
    for (int m = 0; m < 16; ++m) {
      tg = fmaf(xd[m], Wr0[m * 32 + 16 + o], tg);
      v  = fmaf(xd[16 + m * 3 + c], Wr1[m * 16 + o], v);
    }
    float g = 1.0f / (1.0f + expf(-(s_sum[16 + o] + 0.25f * tg)));
    op[16 + jj] = (s_sum[32 + jj] + 0.25f * v) * g;
  }
}

// ---- node epilogue (atomic fallback path) ----
__global__ __launch_bounds__(256) void node_kernel(
    const float* __restrict__ accn, const int* __restrict__ cntp,
    const float* __restrict__ xdst, const float* __restrict__ Wr0,
    const float* __restrict__ Wr1, float* __restrict__ out, int N)
{
  int idx = blockIdx.x * 256 + threadIdx.x;
  int n = idx >> 6, j = idx & 63;
  if (n >= N) return;
  float inv = 1.0f / fmaxf((float)cntp[n], 1.0f);
  const float* ap = accn + (size_t)n * 80;
  const float* xd = xdst + (size_t)n * 64;
  float* op = out + (size_t)n * 64;
  if (j < 16) {
    float s = 0.f;
    #pragma unroll
    for (int m = 0; m < 16; ++m) s = fmaf(xd[m], Wr0[m * 32 + j], s);
    op[j] = fmaxf(ap[j] * inv + 0.25f * s, 0.f);
  } else {
    int jj = j - 16;
    int o = (jj * 86) >> 8;
    int c = jj - o * 3;
    float tg = 0.f, v = 0.f;
    #pragma unroll
    for (int m = 0; m < 16; ++m) {
      tg = fmaf(xd[m], Wr0[m * 32 + 16 + o], tg);
      v  = fmaf(xd[16 + m * 3 + c], Wr1[m * 16 + o], v);
    }
    float g = 1.0f / (1.0f + expf(-(ap[16 + o] * inv + 0.25f * tg)));
    op[16 + jj] = (ap[32 + jj] * inv + 0.25f * v) * g;
  }
}

extern "C" void kernel_launch(void* const* d_in, const int* in_sizes, int n_in,
                              void* d_out, int out_size, void* d_ws, size_t ws_size,
                              hipStream_t stream)
{
  const int*   dst  = (const int*)d_in[0];
  const float* xsrc = (const float*)d_in[1];
  const float* xdst = (const float*)d_in[2];
  const float* sh   = (const float*)d_in[3];
  const float* ea   = (const float*)d_in[4];
  const float* We1  = (const float*)d_in[5];
  const float* be1  = (const float*)d_in[6];
  const float* We2  = (const float*)d_in[7];
  const float* be2  = (const float*)d_in[8];
  const float* Wr0  = (const float*)d_in[9];
  const float* Wr1  = (const float*)d_in[10];
  const int E = in_sizes[0];
  const int N = in_sizes[2] / 64;

  char* ws = (char*)d_ws;
  _Float16* we2h = (_Float16*)ws;                           // 458,752 B
  unsigned short* we1x = (unsigned short*)(ws + 458752);    //  16,384 B
  float* be2p = (float*)(ws + 475136);                      //   7,424 B
  int*   cntp = (int*)(ws + 482560);                        // N*4
  size_t off = 482560 + (size_t)N * 4;
  off = (off + 15) & ~(size_t)15;

  size_t need_msg = off + (size_t)N * MAXDEG * 4 + (size_t)E * 80 * 4;
  bool use_msg = (ws_size >= need_msg);

  prep_kernel<<<(30976 + N + 255) / 256, 256, 0, stream>>>(We1, We2, be2,
      we1x, we2h, be2p, cntp, N);

  if (use_msg) {
    int* eidx = (int*)(ws + off);
    float* msg = (float*)(ws + off + (size_t)N * MAXDEG * 4);
    edge_kernel<true><<<(E + 127) / 128, 256, 0, stream>>>(ea, xsrc, sh, dst, be1,
        we1x, we2h, be2p, msg, eidx, cntp, E);
    node_gather_kernel<<<N, 128, 0, stream>>>(msg, eidx, cntp, xdst, Wr0, Wr1,
        (float*)d_out, N);
  } else {
    float* accn = (float*)(ws + off);
    hipMemsetAsync(accn, 0, (size_t)N * 320, stream);
    edge_kernel<false><<<(E + 127) / 128, 256, 0, stream>>>(ea, xsrc, sh, dst, be1,
        we1x, we2h, be2p, accn, (int*)nullptr, cntp, E);
    node_kernel<<<((size_t)N * 64 + 255) / 256, 256, 0, stream>>>(accn, cntp,
        xdst, Wr0, Wr1, (float*)d_out, N);
  }
}